// Round 1
// baseline (361.893 us; speedup 1.0000x reference)
//
#include <hip/hip_runtime.h>
#include <hip/hip_bf16.h>

#define NPAIRS 524288
#define NATOMS 16384
#define TBINS  2048
#define CUTOFF_F 5.0f

__device__ __forceinline__ float sspf(float v) {
  // softplus(v) - ln2, numerically stable
  float a = fabsf(v);
  return fmaxf(v, 0.0f) + log1pf(expf(-a)) - 0.69314718055994531f;
}

// ---------------- setup kernels ----------------

__global__ __launch_bounds__(256) void zero_kernel(int* __restrict__ p, int n) {
  int i = blockIdx.x * 256 + threadIdx.x;
  if (i < n) p[i] = 0;
}

// pass A: compute all pair distances, histogram surviving pairs per idx_i
__global__ __launch_bounds__(256) void pairs_a(const int* __restrict__ idx_i,
                                               const int* __restrict__ idx_j,
                                               const float* __restrict__ R,
                                               float* __restrict__ d_all,
                                               int* __restrict__ hist) {
  int p = blockIdx.x * 256 + threadIdx.x;  // grid covers NPAIRS exactly
  int i = idx_i[p], j = idx_j[p];
  float dx = R[(size_t)i*3+0] - R[(size_t)j*3+0];
  float dy = R[(size_t)i*3+1] - R[(size_t)j*3+1];
  float dz = R[(size_t)i*3+2] - R[(size_t)j*3+2];
  float d = sqrtf(dx*dx + dy*dy + dz*dz);
  d_all[p] = d;
  if (d < CUTOFF_F) atomicAdd(&hist[i], 1);
}

// exclusive scan of hist[16384] -> offs[16385], also init cursor
__global__ __launch_bounds__(1024) void scan_kernel(const int* __restrict__ hist,
                                                    int* __restrict__ offs,
                                                    int* __restrict__ cursor) {
  __shared__ int sums[1024];
  int t = threadIdx.x;
  int base = t * 16;
  int loc[16]; int s = 0;
  #pragma unroll
  for (int i = 0; i < 16; ++i) { loc[i] = s; s += hist[base + i]; }
  sums[t] = s;
  __syncthreads();
  for (int off = 1; off < 1024; off <<= 1) {
    int v = (t >= off) ? sums[t - off] : 0;
    __syncthreads();
    sums[t] += v;
    __syncthreads();
  }
  int excl = sums[t] - s;  // exclusive prefix of this thread's chunk
  #pragma unroll
  for (int i = 0; i < 16; ++i) {
    int o = excl + loc[i];
    offs[base + i] = o;
    cursor[base + i] = o;
  }
  if (t == 1023) offs[NATOMS] = excl + s;
}

// pass B: place surviving pairs {idx_j, d} into CSR slots
__global__ __launch_bounds__(256) void pairs_b(const int* __restrict__ idx_i,
                                               const int* __restrict__ idx_j,
                                               const float* __restrict__ d_all,
                                               int* __restrict__ cursor,
                                               int2* __restrict__ pjd) {
  int p = blockIdx.x * 256 + threadIdx.x;
  float d = d_all[p];
  if (d < CUTOFF_F) {
    int i = idx_i[p];
    int slot = atomicAdd(&cursor[i], 1);
    pjd[slot] = make_int2(idx_j[p], __float_as_int(d));
  }
}

// embedding: x[a][c] = emb[Z[a]][c]  (x lives in d_out)
__global__ __launch_bounds__(256) void embed_kernel(const int* __restrict__ Z,
                                                    const float* __restrict__ emb,
                                                    float* __restrict__ x) {
  int e = blockIdx.x * 256 + threadIdx.x;  // over 16384*32 float4s
  int a = e >> 5, q = e & 31;
  int z = Z[a];
  ((float4*)x)[(size_t)a * 32 + q] = ((const float4*)emb)[(size_t)z * 32 + q];
}

// ---------------- filter table ----------------
// table[l][t][c] = (ssp(rbf(d_t) @ fW1 + fb1) @ fW2 + fb2)[c] * rcut(d_t),
// d_t = t * CUTOFF/TBINS, t in [0, TBINS]. Row TBINS (d=5) is exactly 0.
__global__ __launch_bounds__(256) void table_kernel(const float* __restrict__ fW1,
                                                    const float* __restrict__ fb1,
                                                    const float* __restrict__ fW2,
                                                    const float* __restrict__ fb2,
                                                    float* __restrict__ table) {
  __shared__ float W2l[64 * 128];
  __shared__ float hid[4][8][128];
  int t = threadIdx.x, w = t >> 6, lane = t & 63;
  int l = blockIdx.x / 65;
  int tbase = (blockIdx.x % 65) * 32;
  const float* W1 = fW1 + (size_t)l * 20 * 128;
  const float* B1 = fb1 + (size_t)l * 128;
  const float* W2 = fW2 + (size_t)l * 128 * 128;
  const float* B2 = fb2 + (size_t)l * 128;

  const float width = CUTOFF_F / 19.0f;
  const float coeff = -0.5f / (width * width);
  const float dstep = CUTOFF_F / (float)TBINS;

  float o[8][2];
  // phase A: hidden activations for this wave's 8 table entries
  for (int e = 0; e < 8; ++e) {
    int ti = tbase + w * 8 + e;
    float d = (float)ti * dstep;
    float h0 = B1[lane], h1 = B1[lane + 64];
    #pragma unroll
    for (int r = 0; r < 20; ++r) {
      float diff = d - (float)r * width;
      float fr = expf(coeff * diff * diff);
      h0 += fr * W1[r * 128 + lane];
      h1 += fr * W1[r * 128 + lane + 64];
    }
    hid[w][e][lane]      = sspf(h0);
    hid[w][e][lane + 64] = sspf(h1);
    o[e][0] = B2[lane];
    o[e][1] = B2[lane + 64];
  }
  // phase B: @ fW2 in two 64-row halves staged in LDS
  for (int half = 0; half < 2; ++half) {
    __syncthreads();
    #pragma unroll
    for (int i = 0; i < 8; ++i) {
      int idx = (i * 256 + t) * 4;
      *(float4*)&W2l[idx] = *(const float4*)&W2[half * 64 * 128 + idx];
    }
    __syncthreads();
    for (int e = 0; e < 8; ++e) {
      #pragma unroll 4
      for (int g = 0; g < 64; ++g) {
        float hg = hid[w][e][half * 64 + g];
        o[e][0] += hg * W2l[g * 128 + lane];
        o[e][1] += hg * W2l[g * 128 + lane + 64];
      }
    }
  }
  for (int e = 0; e < 8; ++e) {
    int ti = tbase + w * 8 + e;
    if (ti <= TBINS) {
      float d = (float)ti * dstep;
      float fc = (d < CUTOFF_F) ? 0.5f * (cosf(d * (3.14159265358979323846f / CUTOFF_F)) + 1.0f) : 0.0f;
      size_t row = ((size_t)l * (TBINS + 1) + ti) * 128;
      table[row + lane]      = o[e][0] * fc;
      table[row + lane + 64] = o[e][1] * fc;
    }
  }
}

// ---------------- GEMM: C[M,128] = f(A[M,128] @ W[128,128] + b) ----------------
// MODE 0: none (h).  MODE 1: ssp.  MODE 2: C += result (residual into x).
template <int MODE>
__global__ __launch_bounds__(256) void gemm128(const float* __restrict__ A,
                                               const float* __restrict__ W,
                                               const float* __restrict__ bias,
                                               float* __restrict__ C) {
  __shared__ float Al[64 * 128];  // 64 rows x 128 k (row-major)
  __shared__ float Wl[64 * 128];  // 64 k-rows x 128 cols (half of W)
  int t = threadIdx.x;
  size_t rbase = (size_t)blockIdx.x * 64;

  // stage A tile
  {
    int kq = t & 31, r0 = t >> 5;
    #pragma unroll
    for (int i = 0; i < 8; ++i) {
      int r = r0 + i * 8;
      *(float4*)&Al[r * 128 + kq * 4] = *(const float4*)&A[(rbase + r) * 128 + kq * 4];
    }
  }

  int tc = t & 31, tr = t >> 5;
  float acc[8][4];
  #pragma unroll
  for (int i = 0; i < 8; ++i) { acc[i][0] = acc[i][1] = acc[i][2] = acc[i][3] = 0.0f; }
  const float* Ab = &Al[(tr * 8) * 128];

  for (int half = 0; half < 2; ++half) {
    __syncthreads();
    #pragma unroll
    for (int i = 0; i < 8; ++i) {
      int idx = (i * 256 + t) * 4;
      *(float4*)&Wl[idx] = *(const float4*)&W[half * 64 * 128 + idx];
    }
    __syncthreads();
    #pragma unroll 2
    for (int k = 0; k < 64; ++k) {
      float4 wv = *(float4*)&Wl[k * 128 + tc * 4];
      int kk = half * 64 + k;
      #pragma unroll
      for (int i = 0; i < 8; ++i) {
        float av = Ab[i * 128 + kk];
        acc[i][0] += av * wv.x;
        acc[i][1] += av * wv.y;
        acc[i][2] += av * wv.z;
        acc[i][3] += av * wv.w;
      }
    }
  }

  float4 bv = *(const float4*)&bias[tc * 4];
  #pragma unroll
  for (int i = 0; i < 8; ++i) {
    size_t row = rbase + tr * 8 + i;
    float4 o;
    o.x = acc[i][0] + bv.x; o.y = acc[i][1] + bv.y;
    o.z = acc[i][2] + bv.z; o.w = acc[i][3] + bv.w;
    if (MODE == 1) { o.x = sspf(o.x); o.y = sspf(o.y); o.z = sspf(o.z); o.w = sspf(o.w); }
    float* dst = C + row * 128 + tc * 4;
    if (MODE == 2) {
      float4 old = *(float4*)dst;
      o.x += old.x; o.y += old.y; o.z += old.z; o.w += old.w;
    }
    *(float4*)dst = o;
  }
}

// ---------------- aggregation: agg[i] = sum_p h[j_p] * lerp(table, d_p) ----------------
__global__ __launch_bounds__(256) void agg_kernel(const int2* __restrict__ pjd,
                                                  const int* __restrict__ offs,
                                                  const float* __restrict__ h,
                                                  const float* __restrict__ table,
                                                  float* __restrict__ agg) {
  int a = blockIdx.x * 4 + (threadIdx.x >> 6);
  int lane = threadIdx.x & 63;
  int p0 = offs[a], p1 = offs[a + 1];
  float ax = 0.0f, ay = 0.0f;
  const float tscale = (float)TBINS / CUTOFF_F;
  int2 nxt = make_int2(0, 0);
  if (p0 < p1) nxt = pjd[p0];
  for (int p = p0; p < p1; ++p) {
    int2 cur = nxt;
    if (p + 1 < p1) nxt = pjd[p + 1];
    int j = cur.x;
    float d = __int_as_float(cur.y);
    float tf = d * tscale;
    int it = (int)tf;
    float fr = tf - (float)it;
    const float* t0 = &table[(size_t)it * 128];
    float2 w0 = *(const float2*)&t0[lane * 2];
    float2 w1 = *(const float2*)&t0[128 + lane * 2];
    float2 hj = *(const float2*)&h[(size_t)j * 128 + lane * 2];
    float wx = w0.x + fr * (w1.x - w0.x);
    float wy = w0.y + fr * (w1.y - w0.y);
    ax += hj.x * wx;
    ay += hj.y * wy;
  }
  float2 res; res.x = ax; res.y = ay;
  *(float2*)&agg[(size_t)a * 128 + lane * 2] = res;
}

// ---------------- launcher ----------------
extern "C" void kernel_launch(void* const* d_in, const int* in_sizes, int n_in,
                              void* d_out, int out_size, void* d_ws, size_t ws_size,
                              hipStream_t stream) {
  const int*   Z      = (const int*)d_in[0];
  const float* R      = (const float*)d_in[1];
  const int*   idx_i  = (const int*)d_in[2];
  const int*   idx_j  = (const int*)d_in[3];
  const float* emb    = (const float*)d_in[4];
  const float* in2f_W = (const float*)d_in[5];
  const float* in2f_b = (const float*)d_in[6];
  const float* fW1    = (const float*)d_in[7];
  const float* fb1    = (const float*)d_in[8];
  const float* fW2    = (const float*)d_in[9];
  const float* fb2    = (const float*)d_in[10];
  const float* oW1    = (const float*)d_in[11];
  const float* ob1    = (const float*)d_in[12];
  const float* oW2    = (const float*)d_in[13];
  const float* ob2    = (const float*)d_in[14];
  float* x = (float*)d_out;  // x accumulates in d_out across layers

  char* ws = (char*)d_ws;
  float* d_all  = (float*)(ws + 0x000000);            // 2 MB
  int*   hist   = (int*)  (ws + 0x200000);            // 64 KB
  int*   cursor = (int*)  (ws + 0x210000);            // 64 KB
  int*   offs   = (int*)  (ws + 0x220000);            // 64 KB + 4
  int2*  pjd    = (int2*) (ws + 0x240000);            // 4 MB
  float* table  = (float*)(ws + 0x640000);            // 3.003 MB (3 x 2049 x 128)
  float* h      = (float*)(ws + 0xA00000);            // 8 MB
  float* agg    = (float*)(ws + 0x1200000);           // 8 MB
  float* t1     = (float*)(ws + 0x1A00000);           // 8 MB

  zero_kernel<<<64, 256, 0, stream>>>(hist, NATOMS);
  pairs_a<<<NPAIRS / 256, 256, 0, stream>>>(idx_i, idx_j, R, d_all, hist);
  scan_kernel<<<1, 1024, 0, stream>>>(hist, offs, cursor);
  pairs_b<<<NPAIRS / 256, 256, 0, stream>>>(idx_i, idx_j, d_all, cursor, pjd);
  table_kernel<<<3 * 65, 256, 0, stream>>>(fW1, fb1, fW2, fb2, table);
  embed_kernel<<<(NATOMS * 32) / 256, 256, 0, stream>>>(Z, emb, x);

  for (int l = 0; l < 3; ++l) {
    gemm128<0><<<NATOMS / 64, 256, 0, stream>>>(x, in2f_W + (size_t)l * 128 * 128,
                                                in2f_b + (size_t)l * 128, h);
    agg_kernel<<<NATOMS / 4, 256, 0, stream>>>(pjd, offs, h,
                                               table + (size_t)l * (TBINS + 1) * 128, agg);
    gemm128<1><<<NATOMS / 64, 256, 0, stream>>>(agg, oW1 + (size_t)l * 128 * 128,
                                                ob1 + (size_t)l * 128, t1);
    gemm128<2><<<NATOMS / 64, 256, 0, stream>>>(t1, oW2 + (size_t)l * 128 * 128,
                                                ob2 + (size_t)l * 128, x);
  }
}

// Round 2
// 272.798 us; speedup vs baseline: 1.3266x; 1.3266x over previous
//
#include <hip/hip_runtime.h>
#include <hip/hip_bf16.h>
#include <hip/hip_fp16.h>

#define NPAIRS 524288
#define NATOMS 16384
#define TBINS  2048
#define TROWS  2050   // rows per layer: 0..2047 lerp base, 2048 zero (d=5), 2049 zero (tail pad)
#define CUTOFF_F 5.0f

__device__ __forceinline__ float sspf(float v) {
  float a = fabsf(v);
  return fmaxf(v, 0.0f) + log1pf(expf(-a)) - 0.69314718055994531f;
}

__device__ __forceinline__ float2 h2f(unsigned u) {
  __half2 h = *reinterpret_cast<__half2*>(&u);
  return __half22float2(h);
}

// ---------------- setup kernels ----------------

__global__ __launch_bounds__(256) void zero_kernel(int* __restrict__ p, int n) {
  int i = blockIdx.x * 256 + threadIdx.x;
  if (i < n) p[i] = 0;
}

__global__ __launch_bounds__(256) void pairs_a(const int* __restrict__ idx_i,
                                               const int* __restrict__ idx_j,
                                               const float* __restrict__ R,
                                               float* __restrict__ d_all,
                                               int* __restrict__ hist) {
  int p = blockIdx.x * 256 + threadIdx.x;
  int i = idx_i[p], j = idx_j[p];
  float dx = R[(size_t)i*3+0] - R[(size_t)j*3+0];
  float dy = R[(size_t)i*3+1] - R[(size_t)j*3+1];
  float dz = R[(size_t)i*3+2] - R[(size_t)j*3+2];
  float d = sqrtf(dx*dx + dy*dy + dz*dz);
  d_all[p] = d;
  if (d < CUTOFF_F) atomicAdd(&hist[i], 1);
}

__global__ __launch_bounds__(1024) void scan_kernel(const int* __restrict__ hist,
                                                    int* __restrict__ offs,
                                                    int* __restrict__ cursor) {
  __shared__ int sums[1024];
  int t = threadIdx.x;
  int base = t * 16;
  int loc[16]; int s = 0;
  #pragma unroll
  for (int i = 0; i < 16; ++i) { loc[i] = s; s += hist[base + i]; }
  sums[t] = s;
  __syncthreads();
  for (int off = 1; off < 1024; off <<= 1) {
    int v = (t >= off) ? sums[t - off] : 0;
    __syncthreads();
    sums[t] += v;
    __syncthreads();
  }
  int excl = sums[t] - s;
  #pragma unroll
  for (int i = 0; i < 16; ++i) {
    int o = excl + loc[i];
    offs[base + i] = o;
    cursor[base + i] = o;
  }
  if (t == 1023) offs[NATOMS] = excl + s;
}

__global__ __launch_bounds__(256) void pairs_b(const int* __restrict__ idx_i,
                                               const int* __restrict__ idx_j,
                                               const float* __restrict__ d_all,
                                               int* __restrict__ cursor,
                                               int2* __restrict__ pjd) {
  int p = blockIdx.x * 256 + threadIdx.x;
  float d = d_all[p];
  if (d < CUTOFF_F) {
    int i = idx_i[p];
    int slot = atomicAdd(&cursor[i], 1);
    pjd[slot] = make_int2(idx_j[p], __float_as_int(d));
  }
}

__global__ __launch_bounds__(256) void embed_kernel(const int* __restrict__ Z,
                                                    const float* __restrict__ emb,
                                                    float* __restrict__ x) {
  int e = blockIdx.x * 256 + threadIdx.x;
  int a = e >> 5, q = e & 31;
  int z = Z[a];
  ((float4*)x)[(size_t)a * 32 + q] = ((const float4*)emb)[(size_t)z * 32 + q];
}

// ---------------- filter table (fp16 output) ----------------
__global__ __launch_bounds__(256) void table_kernel(const float* __restrict__ fW1,
                                                    const float* __restrict__ fb1,
                                                    const float* __restrict__ fW2,
                                                    const float* __restrict__ fb2,
                                                    __half* __restrict__ table) {
  __shared__ float W2l[64 * 128];
  __shared__ float hid[4][8][128];
  int t = threadIdx.x, w = t >> 6, lane = t & 63;
  int l = blockIdx.x / 65;
  int tbase = (blockIdx.x % 65) * 32;
  const float* W1 = fW1 + (size_t)l * 20 * 128;
  const float* B1 = fb1 + (size_t)l * 128;
  const float* W2 = fW2 + (size_t)l * 128 * 128;
  const float* B2 = fb2 + (size_t)l * 128;

  const float width = CUTOFF_F / 19.0f;
  const float coeff = -0.5f / (width * width);
  const float dstep = CUTOFF_F / (float)TBINS;

  float o[8][2];
  for (int e = 0; e < 8; ++e) {
    int ti = tbase + w * 8 + e;
    float d = (float)ti * dstep;
    float h0 = B1[lane], h1 = B1[lane + 64];
    #pragma unroll
    for (int r = 0; r < 20; ++r) {
      float diff = d - (float)r * width;
      float fr = expf(coeff * diff * diff);
      h0 += fr * W1[r * 128 + lane];
      h1 += fr * W1[r * 128 + lane + 64];
    }
    hid[w][e][lane]      = sspf(h0);
    hid[w][e][lane + 64] = sspf(h1);
    o[e][0] = B2[lane];
    o[e][1] = B2[lane + 64];
  }
  for (int half = 0; half < 2; ++half) {
    __syncthreads();
    #pragma unroll
    for (int i = 0; i < 8; ++i) {
      int idx = (i * 256 + t) * 4;
      *(float4*)&W2l[idx] = *(const float4*)&W2[half * 64 * 128 + idx];
    }
    __syncthreads();
    for (int e = 0; e < 8; ++e) {
      #pragma unroll 4
      for (int g = 0; g < 64; ++g) {
        float hg = hid[w][e][half * 64 + g];
        o[e][0] += hg * W2l[g * 128 + lane];
        o[e][1] += hg * W2l[g * 128 + lane + 64];
      }
    }
  }
  for (int e = 0; e < 8; ++e) {
    int ti = tbase + w * 8 + e;
    if (ti < TROWS) {
      float d = (float)ti * dstep;
      float fc = (d < CUTOFF_F) ? 0.5f * (cosf(d * (3.14159265358979323846f / CUTOFF_F)) + 1.0f) : 0.0f;
      size_t row = ((size_t)l * TROWS + ti) * 128;
      table[row + lane]      = __float2half(o[e][0] * fc);
      table[row + lane + 64] = __float2half(o[e][1] * fc);
    }
  }
}

// ---------------- GEMM: 32-row tiles, grid 512, 2 blocks/CU ----------------
// MODE 0: out fp16 -> Ch.  MODE 1: ssp, out fp32 -> C.  MODE 2: C += result.
template <int MODE>
__global__ __launch_bounds__(256) void gemm32(const float* __restrict__ A,
                                              const float* __restrict__ W,
                                              const float* __restrict__ bias,
                                              float* __restrict__ C,
                                              __half* __restrict__ Ch) {
  __shared__ float Al[32 * 128];   // 16 KB
  __shared__ float Wl[128 * 128];  // 64 KB
  int t = threadIdx.x;
  size_t rbase = (size_t)blockIdx.x * 32;

  {
    const float4* Ag = (const float4*)(A + rbase * 128);
    #pragma unroll
    for (int i = 0; i < 4; ++i) {
      int idx = i * 256 + t;
      ((float4*)Al)[idx] = Ag[idx];
    }
    const float4* Wg = (const float4*)W;
    #pragma unroll
    for (int i = 0; i < 16; ++i) {
      int idx = i * 256 + t;
      ((float4*)Wl)[idx] = Wg[idx];
    }
  }
  __syncthreads();

  int tc = t & 31, tr = t >> 5;   // 8 row-groups x 32 col-groups
  const float* Ab = &Al[(tr * 4) * 128];
  float acc[4][4];
  #pragma unroll
  for (int i = 0; i < 4; ++i) { acc[i][0] = acc[i][1] = acc[i][2] = acc[i][3] = 0.0f; }

  for (int k = 0; k < 128; k += 4) {
    float4 w0 = *(float4*)&Wl[(k + 0) * 128 + tc * 4];
    float4 w1 = *(float4*)&Wl[(k + 1) * 128 + tc * 4];
    float4 w2 = *(float4*)&Wl[(k + 2) * 128 + tc * 4];
    float4 w3 = *(float4*)&Wl[(k + 3) * 128 + tc * 4];
    #pragma unroll
    for (int i = 0; i < 4; ++i) {
      float4 av = *(float4*)&Ab[i * 128 + k];
      acc[i][0] += av.x * w0.x + av.y * w1.x + av.z * w2.x + av.w * w3.x;
      acc[i][1] += av.x * w0.y + av.y * w1.y + av.z * w2.y + av.w * w3.y;
      acc[i][2] += av.x * w0.z + av.y * w1.z + av.z * w2.z + av.w * w3.z;
      acc[i][3] += av.x * w0.w + av.y * w1.w + av.z * w2.w + av.w * w3.w;
    }
  }

  float4 bv = *(const float4*)&bias[tc * 4];
  #pragma unroll
  for (int i = 0; i < 4; ++i) {
    size_t row = rbase + tr * 4 + i;
    float ox = acc[i][0] + bv.x, oy = acc[i][1] + bv.y;
    float oz = acc[i][2] + bv.z, ow = acc[i][3] + bv.w;
    if (MODE == 1) { ox = sspf(ox); oy = sspf(oy); oz = sspf(oz); ow = sspf(ow); }
    if (MODE == 0) {
      __half2* dst = (__half2*)(Ch + row * 128 + tc * 4);
      dst[0] = __floats2half2_rn(ox, oy);
      dst[1] = __floats2half2_rn(oz, ow);
    } else {
      float* dst = C + row * 128 + tc * 4;
      float4 o = make_float4(ox, oy, oz, ow);
      if (MODE == 2) {
        float4 old = *(float4*)dst;
        o.x += old.x; o.y += old.y; o.z += old.z; o.w += old.w;
      }
      *(float4*)dst = o;
    }
  }
}

// ---------------- aggregation: 4 pairs/wave-iter, fp16 table+h ----------------
__global__ __launch_bounds__(256) void agg_kernel(const int2* __restrict__ pjd,
                                                  const int* __restrict__ offs,
                                                  const __half* __restrict__ h,
                                                  const __half* __restrict__ table,
                                                  float* __restrict__ agg) {
  int a = blockIdx.x * 4 + (threadIdx.x >> 6);
  int lane = threadIdx.x & 63;
  int g = lane >> 4;     // pair slot within iteration
  int c = lane & 15;     // column group: cols c*8 .. c*8+7
  int p0 = offs[a], p1 = offs[a + 1];
  int n = p1 - p0;
  float acc[8];
  #pragma unroll
  for (int q = 0; q < 8; ++q) acc[q] = 0.0f;
  const float tscale = (float)TBINS / CUTOFF_F;

  for (int base = 0; base < n; base += 4) {
    int off = base + g;
    bool valid = off < n;
    int pc = valid ? (p0 + off) : p0;
    int2 jd = pjd[pc];
    int it0; float fr;
    if (valid) {
      float tf = __int_as_float(jd.y) * tscale;
      it0 = (int)tf;
      fr = tf - (float)it0;
    } else {
      it0 = TBINS;   // rows TBINS and TBINS+1 are all zeros -> contributes 0
      fr = 0.0f;
    }
    const __half* t0 = table + (size_t)it0 * 128 + c * 8;
    uint4 w0 = *(const uint4*)t0;
    uint4 w1 = *(const uint4*)(t0 + 128);
    uint4 hv = *(const uint4*)(h + (size_t)jd.x * 128 + c * 8);
    const unsigned* w0a = (const unsigned*)&w0;
    const unsigned* w1a = (const unsigned*)&w1;
    const unsigned* hva = (const unsigned*)&hv;
    #pragma unroll
    for (int q = 0; q < 4; ++q) {
      float2 wa = h2f(w0a[q]);
      float2 wb = h2f(w1a[q]);
      float2 hh = h2f(hva[q]);
      float wx = fmaf(fr, wb.x - wa.x, wa.x);
      float wy = fmaf(fr, wb.y - wa.y, wa.y);
      acc[2*q]   += hh.x * wx;
      acc[2*q+1] += hh.y * wy;
    }
  }

  #pragma unroll
  for (int q = 0; q < 8; ++q) {
    acc[q] += __shfl_xor(acc[q], 16, 64);
    acc[q] += __shfl_xor(acc[q], 32, 64);
  }
  if (g == 0) {
    float4 o0 = make_float4(acc[0], acc[1], acc[2], acc[3]);
    float4 o1 = make_float4(acc[4], acc[5], acc[6], acc[7]);
    *(float4*)&agg[(size_t)a * 128 + c * 8]     = o0;
    *(float4*)&agg[(size_t)a * 128 + c * 8 + 4] = o1;
  }
}

// ---------------- launcher ----------------
extern "C" void kernel_launch(void* const* d_in, const int* in_sizes, int n_in,
                              void* d_out, int out_size, void* d_ws, size_t ws_size,
                              hipStream_t stream) {
  const int*   Z      = (const int*)d_in[0];
  const float* R      = (const float*)d_in[1];
  const int*   idx_i  = (const int*)d_in[2];
  const int*   idx_j  = (const int*)d_in[3];
  const float* emb    = (const float*)d_in[4];
  const float* in2f_W = (const float*)d_in[5];
  const float* in2f_b = (const float*)d_in[6];
  const float* fW1    = (const float*)d_in[7];
  const float* fb1    = (const float*)d_in[8];
  const float* fW2    = (const float*)d_in[9];
  const float* fb2    = (const float*)d_in[10];
  const float* oW1    = (const float*)d_in[11];
  const float* ob1    = (const float*)d_in[12];
  const float* oW2    = (const float*)d_in[13];
  const float* ob2    = (const float*)d_in[14];
  float* x = (float*)d_out;

  char* ws = (char*)d_ws;
  float*  d_all  = (float*) (ws + 0x000000);   // 2 MB
  int*    hist   = (int*)   (ws + 0x200000);   // 64 KB
  int*    cursor = (int*)   (ws + 0x210000);   // 64 KB
  int*    offs   = (int*)   (ws + 0x220000);   // 128 KB
  int2*   pjd    = (int2*)  (ws + 0x240000);   // 4 MB
  __half* table  = (__half*)(ws + 0x640000);   // 3 x 2050 x 128 x 2B = 1.54 MB
  __half* h_h    = (__half*)(ws + 0x800000);   // 4 MB
  float*  agg    = (float*) (ws + 0xC00000);   // 8 MB
  float*  t1     = (float*) (ws + 0x1400000);  // 8 MB

  zero_kernel<<<64, 256, 0, stream>>>(hist, NATOMS);
  pairs_a<<<NPAIRS / 256, 256, 0, stream>>>(idx_i, idx_j, R, d_all, hist);
  scan_kernel<<<1, 1024, 0, stream>>>(hist, offs, cursor);
  pairs_b<<<NPAIRS / 256, 256, 0, stream>>>(idx_i, idx_j, d_all, cursor, pjd);
  table_kernel<<<3 * 65, 256, 0, stream>>>(fW1, fb1, fW2, fb2, table);
  embed_kernel<<<(NATOMS * 32) / 256, 256, 0, stream>>>(Z, emb, x);

  for (int l = 0; l < 3; ++l) {
    gemm32<0><<<NATOMS / 32, 256, 0, stream>>>(x, in2f_W + (size_t)l * 128 * 128,
                                               in2f_b + (size_t)l * 128, nullptr, h_h);
    agg_kernel<<<NATOMS / 4, 256, 0, stream>>>(pjd, offs, h_h,
                                               table + (size_t)l * TROWS * 128, agg);
    gemm32<1><<<NATOMS / 32, 256, 0, stream>>>(agg, oW1 + (size_t)l * 128 * 128,
                                               ob1 + (size_t)l * 128, t1, nullptr);
    gemm32<2><<<NATOMS / 32, 256, 0, stream>>>(t1, oW2 + (size_t)l * 128 * 128,
                                               ob2 + (size_t)l * 128, x, nullptr);
  }
}

// Round 3
// 262.402 us; speedup vs baseline: 1.3792x; 1.0396x over previous
//
#include <hip/hip_runtime.h>
#include <hip/hip_bf16.h>
#include <hip/hip_fp16.h>

#define NPAIRS 524288
#define NATOMS 16384
#define TBINS  2048
#define TROWS  2050   // rows/layer: 0..2047 lerp base, 2048 zero (d=5), 2049 zero (pad)
#define CUTOFF_F 5.0f

__device__ __forceinline__ float sspf(float v) {
  float a = fabsf(v);
  return fmaxf(v, 0.0f) + log1pf(expf(-a)) - 0.69314718055994531f;
}

__device__ __forceinline__ float2 h2f(unsigned u) {
  __half2 h = *reinterpret_cast<__half2*>(&u);
  return __half22float2(h);
}

// ---------------- setup kernels ----------------

__global__ __launch_bounds__(256) void zero_kernel(int* __restrict__ p, int n) {
  int i = blockIdx.x * 256 + threadIdx.x;
  if (i < n) p[i] = 0;
}

__global__ __launch_bounds__(256) void pairs_a(const int* __restrict__ idx_i,
                                               const int* __restrict__ idx_j,
                                               const float* __restrict__ R,
                                               float* __restrict__ d_all,
                                               int* __restrict__ hist) {
  int p = blockIdx.x * 256 + threadIdx.x;
  int i = idx_i[p], j = idx_j[p];
  float dx = R[(size_t)i*3+0] - R[(size_t)j*3+0];
  float dy = R[(size_t)i*3+1] - R[(size_t)j*3+1];
  float dz = R[(size_t)i*3+2] - R[(size_t)j*3+2];
  float d = sqrtf(dx*dx + dy*dy + dz*dz);
  d_all[p] = d;
  if (d < CUTOFF_F) atomicAdd(&hist[i], 1);
}

__global__ __launch_bounds__(1024) void scan_kernel(const int* __restrict__ hist,
                                                    int* __restrict__ offs,
                                                    int* __restrict__ cursor) {
  __shared__ int sums[1024];
  int t = threadIdx.x;
  int base = t * 16;
  int loc[16]; int s = 0;
  #pragma unroll
  for (int i = 0; i < 16; ++i) { loc[i] = s; s += hist[base + i]; }
  sums[t] = s;
  __syncthreads();
  for (int off = 1; off < 1024; off <<= 1) {
    int v = (t >= off) ? sums[t - off] : 0;
    __syncthreads();
    sums[t] += v;
    __syncthreads();
  }
  int excl = sums[t] - s;
  #pragma unroll
  for (int i = 0; i < 16; ++i) {
    int o = excl + loc[i];
    offs[base + i] = o;
    cursor[base + i] = o;
  }
  if (t == 1023) offs[NATOMS] = excl + s;
}

__global__ __launch_bounds__(256) void pairs_b(const int* __restrict__ idx_i,
                                               const int* __restrict__ idx_j,
                                               const float* __restrict__ d_all,
                                               int* __restrict__ cursor,
                                               int2* __restrict__ pjd) {
  int p = blockIdx.x * 256 + threadIdx.x;
  float d = d_all[p];
  if (d < CUTOFF_F) {
    int i = idx_i[p];
    int slot = atomicAdd(&cursor[i], 1);
    pjd[slot] = make_int2(idx_j[p], __float_as_int(d));
  }
}

__global__ __launch_bounds__(256) void embed_kernel(const int* __restrict__ Z,
                                                    const float* __restrict__ emb,
                                                    float* __restrict__ x) {
  int e = blockIdx.x * 256 + threadIdx.x;
  int a = e >> 5, q = e & 31;
  int z = Z[a];
  ((float4*)x)[(size_t)a * 32 + q] = ((const float4*)emb)[(size_t)z * 32 + q];
}

// ---------------- filter table (fp16 output) ----------------
__global__ __launch_bounds__(256) void table_kernel(const float* __restrict__ fW1,
                                                    const float* __restrict__ fb1,
                                                    const float* __restrict__ fW2,
                                                    const float* __restrict__ fb2,
                                                    __half* __restrict__ table) {
  __shared__ float W2l[64 * 128];
  __shared__ float hid[4][8][128];
  int t = threadIdx.x, w = t >> 6, lane = t & 63;
  int l = blockIdx.x / 65;
  int tbase = (blockIdx.x % 65) * 32;
  const float* W1 = fW1 + (size_t)l * 20 * 128;
  const float* B1 = fb1 + (size_t)l * 128;
  const float* W2 = fW2 + (size_t)l * 128 * 128;
  const float* B2 = fb2 + (size_t)l * 128;

  const float width = CUTOFF_F / 19.0f;
  const float coeff = -0.5f / (width * width);
  const float dstep = CUTOFF_F / (float)TBINS;

  float o[8][2];
  for (int e = 0; e < 8; ++e) {
    int ti = tbase + w * 8 + e;
    float d = (float)ti * dstep;
    float h0 = B1[lane], h1 = B1[lane + 64];
    #pragma unroll
    for (int r = 0; r < 20; ++r) {
      float diff = d - (float)r * width;
      float fr = expf(coeff * diff * diff);
      h0 += fr * W1[r * 128 + lane];
      h1 += fr * W1[r * 128 + lane + 64];
    }
    hid[w][e][lane]      = sspf(h0);
    hid[w][e][lane + 64] = sspf(h1);
    o[e][0] = B2[lane];
    o[e][1] = B2[lane + 64];
  }
  for (int half = 0; half < 2; ++half) {
    __syncthreads();
    #pragma unroll
    for (int i = 0; i < 8; ++i) {
      int idx = (i * 256 + t) * 4;
      *(float4*)&W2l[idx] = *(const float4*)&W2[half * 64 * 128 + idx];
    }
    __syncthreads();
    for (int e = 0; e < 8; ++e) {
      #pragma unroll 4
      for (int g = 0; g < 64; ++g) {
        float hg = hid[w][e][half * 64 + g];
        o[e][0] += hg * W2l[g * 128 + lane];
        o[e][1] += hg * W2l[g * 128 + lane + 64];
      }
    }
  }
  for (int e = 0; e < 8; ++e) {
    int ti = tbase + w * 8 + e;
    if (ti < TROWS) {
      float d = (float)ti * dstep;
      float fc = (d < CUTOFF_F) ? 0.5f * (cosf(d * (3.14159265358979323846f / CUTOFF_F)) + 1.0f) : 0.0f;
      size_t row = ((size_t)l * TROWS + ti) * 128;
      table[row + lane]      = __float2half(o[e][0] * fc);
      table[row + lane + 64] = __float2half(o[e][1] * fc);
    }
  }
}

// ---------------- gemm_in: h = x @ W + b  (fp16 out), 64-row tiles ----------------
__global__ __launch_bounds__(512) void gemm_in(const float* __restrict__ A,
                                               const float* __restrict__ W,
                                               const float* __restrict__ bias,
                                               __half* __restrict__ Ch) {
  __shared__ float Al[64 * 128];   // 32 KB
  __shared__ float Wl[128 * 128];  // 64 KB
  int t = threadIdx.x;
  size_t rbase = (size_t)blockIdx.x * 64;

  const float4* Ag = (const float4*)(A + rbase * 128);
  #pragma unroll
  for (int i = 0; i < 4; ++i) ((float4*)Al)[i * 512 + t] = Ag[i * 512 + t];
  const float4* Wg = (const float4*)W;
  #pragma unroll
  for (int i = 0; i < 8; ++i) ((float4*)Wl)[i * 512 + t] = Wg[i * 512 + t];
  __syncthreads();

  int tc = t & 31, tr = t >> 5;  // 16 row-groups x 32 col-groups
  const float* Ab = &Al[(tr * 4) * 128];
  float acc[4][4];
  #pragma unroll
  for (int i = 0; i < 4; ++i) { acc[i][0] = acc[i][1] = acc[i][2] = acc[i][3] = 0.0f; }

  for (int k = 0; k < 128; k += 4) {
    float4 w0 = *(float4*)&Wl[(k + 0) * 128 + tc * 4];
    float4 w1 = *(float4*)&Wl[(k + 1) * 128 + tc * 4];
    float4 w2 = *(float4*)&Wl[(k + 2) * 128 + tc * 4];
    float4 w3 = *(float4*)&Wl[(k + 3) * 128 + tc * 4];
    #pragma unroll
    for (int i = 0; i < 4; ++i) {
      float4 av = *(float4*)&Ab[i * 128 + k];
      acc[i][0] += av.x * w0.x + av.y * w1.x + av.z * w2.x + av.w * w3.x;
      acc[i][1] += av.x * w0.y + av.y * w1.y + av.z * w2.y + av.w * w3.y;
      acc[i][2] += av.x * w0.z + av.y * w1.z + av.z * w2.z + av.w * w3.z;
      acc[i][3] += av.x * w0.w + av.y * w1.w + av.z * w2.w + av.w * w3.w;
    }
  }

  float4 bv = *(const float4*)&bias[tc * 4];
  #pragma unroll
  for (int i = 0; i < 4; ++i) {
    size_t row = rbase + tr * 4 + i;
    __half2 ha = __floats2half2_rn(acc[i][0] + bv.x, acc[i][1] + bv.y);
    __half2 hb = __floats2half2_rn(acc[i][2] + bv.z, acc[i][3] + bv.w);
    uint2 pk = make_uint2(*(unsigned*)&ha, *(unsigned*)&hb);
    *(uint2*)(Ch + row * 128 + tc * 4) = pk;
  }
}

// ---------------- fused output MLP: x += ssp(agg@oW1+b1)@oW2 + b2 ----------------
__global__ __launch_bounds__(512) void out_mlp(const float* __restrict__ agg,
                                               const float* __restrict__ oW1,
                                               const float* __restrict__ ob1,
                                               const float* __restrict__ oW2,
                                               const float* __restrict__ ob2,
                                               float* __restrict__ x) {
  __shared__ float Al[64 * 128];   // 32 KB: agg tile
  __shared__ float Wl[128 * 128];  // 64 KB: oW1, then oW2
  __shared__ float Tl[64 * 128];   // 32 KB: hidden
  int t = threadIdx.x;
  size_t rbase = (size_t)blockIdx.x * 64;

  const float4* Ag = (const float4*)(agg + rbase * 128);
  #pragma unroll
  for (int i = 0; i < 4; ++i) ((float4*)Al)[i * 512 + t] = Ag[i * 512 + t];
  const float4* W1g = (const float4*)oW1;
  #pragma unroll
  for (int i = 0; i < 8; ++i) ((float4*)Wl)[i * 512 + t] = W1g[i * 512 + t];
  __syncthreads();

  int tc = t & 31, tr = t >> 5;
  float acc[4][4];

  // gemm1: Tl = ssp(Al @ oW1 + b1)
  {
    const float* Ab = &Al[(tr * 4) * 128];
    #pragma unroll
    for (int i = 0; i < 4; ++i) { acc[i][0] = acc[i][1] = acc[i][2] = acc[i][3] = 0.0f; }
    for (int k = 0; k < 128; k += 4) {
      float4 w0 = *(float4*)&Wl[(k + 0) * 128 + tc * 4];
      float4 w1 = *(float4*)&Wl[(k + 1) * 128 + tc * 4];
      float4 w2 = *(float4*)&Wl[(k + 2) * 128 + tc * 4];
      float4 w3 = *(float4*)&Wl[(k + 3) * 128 + tc * 4];
      #pragma unroll
      for (int i = 0; i < 4; ++i) {
        float4 av = *(float4*)&Ab[i * 128 + k];
        acc[i][0] += av.x * w0.x + av.y * w1.x + av.z * w2.x + av.w * w3.x;
        acc[i][1] += av.x * w0.y + av.y * w1.y + av.z * w2.y + av.w * w3.y;
        acc[i][2] += av.x * w0.z + av.y * w1.z + av.z * w2.z + av.w * w3.z;
        acc[i][3] += av.x * w0.w + av.y * w1.w + av.z * w2.w + av.w * w3.w;
      }
    }
    float4 bv = *(const float4*)&ob1[tc * 4];
    #pragma unroll
    for (int i = 0; i < 4; ++i) {
      float* dst = &Tl[(tr * 4 + i) * 128 + tc * 4];
      dst[0] = sspf(acc[i][0] + bv.x);
      dst[1] = sspf(acc[i][1] + bv.y);
      dst[2] = sspf(acc[i][2] + bv.z);
      dst[3] = sspf(acc[i][3] + bv.w);
    }
  }
  __syncthreads();

  // restage Wl = oW2
  const float4* W2g = (const float4*)oW2;
  #pragma unroll
  for (int i = 0; i < 8; ++i) ((float4*)Wl)[i * 512 + t] = W2g[i * 512 + t];
  __syncthreads();

  // gemm2: x += Tl @ oW2 + b2
  {
    const float* Ab = &Tl[(tr * 4) * 128];
    #pragma unroll
    for (int i = 0; i < 4; ++i) { acc[i][0] = acc[i][1] = acc[i][2] = acc[i][3] = 0.0f; }
    for (int k = 0; k < 128; k += 4) {
      float4 w0 = *(float4*)&Wl[(k + 0) * 128 + tc * 4];
      float4 w1 = *(float4*)&Wl[(k + 1) * 128 + tc * 4];
      float4 w2 = *(float4*)&Wl[(k + 2) * 128 + tc * 4];
      float4 w3 = *(float4*)&Wl[(k + 3) * 128 + tc * 4];
      #pragma unroll
      for (int i = 0; i < 4; ++i) {
        float4 av = *(float4*)&Ab[i * 128 + k];
        acc[i][0] += av.x * w0.x + av.y * w1.x + av.z * w2.x + av.w * w3.x;
        acc[i][1] += av.x * w0.y + av.y * w1.y + av.z * w2.y + av.w * w3.y;
        acc[i][2] += av.x * w0.z + av.y * w1.z + av.z * w2.z + av.w * w3.z;
        acc[i][3] += av.x * w0.w + av.y * w1.w + av.z * w2.w + av.w * w3.w;
      }
    }
    float4 bv = *(const float4*)&ob2[tc * 4];
    #pragma unroll
    for (int i = 0; i < 4; ++i) {
      size_t row = rbase + tr * 4 + i;
      float* dst = (float*)(x + row * 128 + tc * 4);
      float4 old = *(float4*)dst;
      float4 o;
      o.x = old.x + acc[i][0] + bv.x;
      o.y = old.y + acc[i][1] + bv.y;
      o.z = old.z + acc[i][2] + bv.z;
      o.w = old.w + acc[i][3] + bv.w;
      *(float4*)dst = o;
    }
  }
}

// ---------------- aggregation: 8 pairs/wave-iter, pjd prefetch ----------------
__global__ __launch_bounds__(256) void agg_kernel(const int2* __restrict__ pjd,
                                                  const int* __restrict__ offs,
                                                  const __half* __restrict__ h,
                                                  const __half* __restrict__ table,
                                                  float* __restrict__ agg) {
  int a = blockIdx.x * 4 + (threadIdx.x >> 6);
  int lane = threadIdx.x & 63;
  int g = lane >> 4;     // 0..3
  int c = lane & 15;     // column group: cols c*8 .. c*8+7
  int p0 = offs[a], p1 = offs[a + 1];
  int n = p1 - p0;
  const float tscale = (float)TBINS / CUTOFF_F;
  const int2 sentinel = make_int2(0, __float_as_int(CUTOFF_F));  // -> zero table rows

  float acc[8];
  #pragma unroll
  for (int q = 0; q < 8; ++q) acc[q] = 0.0f;

  int2 jdA = (g < n) ? pjd[p0 + g] : sentinel;
  int2 jdB = (g + 4 < n) ? pjd[p0 + g + 4] : sentinel;

  for (int base = 0; base < n; base += 8) {
    int nA = base + 8 + g, nB = base + 12 + g;
    int2 jdA_n = (nA < n) ? pjd[p0 + nA] : sentinel;
    int2 jdB_n = (nB < n) ? pjd[p0 + nB] : sentinel;

    float tfA = __int_as_float(jdA.y) * tscale;
    int itA = (int)tfA; float frA = tfA - (float)itA;
    float tfB = __int_as_float(jdB.y) * tscale;
    int itB = (int)tfB; float frB = tfB - (float)itB;

    const __half* tA = table + (size_t)itA * 128 + c * 8;
    const __half* tB = table + (size_t)itB * 128 + c * 8;
    uint4 w0A = *(const uint4*)tA;
    uint4 w1A = *(const uint4*)(tA + 128);
    uint4 hvA = *(const uint4*)(h + (size_t)jdA.x * 128 + c * 8);
    uint4 w0B = *(const uint4*)tB;
    uint4 w1B = *(const uint4*)(tB + 128);
    uint4 hvB = *(const uint4*)(h + (size_t)jdB.x * 128 + c * 8);

    {
      const unsigned* w0a = (const unsigned*)&w0A;
      const unsigned* w1a = (const unsigned*)&w1A;
      const unsigned* hva = (const unsigned*)&hvA;
      #pragma unroll
      for (int q = 0; q < 4; ++q) {
        float2 wa = h2f(w0a[q]), wb = h2f(w1a[q]), hh = h2f(hva[q]);
        acc[2*q]   += hh.x * fmaf(frA, wb.x - wa.x, wa.x);
        acc[2*q+1] += hh.y * fmaf(frA, wb.y - wa.y, wa.y);
      }
    }
    {
      const unsigned* w0a = (const unsigned*)&w0B;
      const unsigned* w1a = (const unsigned*)&w1B;
      const unsigned* hva = (const unsigned*)&hvB;
      #pragma unroll
      for (int q = 0; q < 4; ++q) {
        float2 wa = h2f(w0a[q]), wb = h2f(w1a[q]), hh = h2f(hva[q]);
        acc[2*q]   += hh.x * fmaf(frB, wb.x - wa.x, wa.x);
        acc[2*q+1] += hh.y * fmaf(frB, wb.y - wa.y, wa.y);
      }
    }
    jdA = jdA_n; jdB = jdB_n;
  }

  #pragma unroll
  for (int q = 0; q < 8; ++q) {
    acc[q] += __shfl_xor(acc[q], 16, 64);
    acc[q] += __shfl_xor(acc[q], 32, 64);
  }
  if (g == 0) {
    float4 o0 = make_float4(acc[0], acc[1], acc[2], acc[3]);
    float4 o1 = make_float4(acc[4], acc[5], acc[6], acc[7]);
    *(float4*)&agg[(size_t)a * 128 + c * 8]     = o0;
    *(float4*)&agg[(size_t)a * 128 + c * 8 + 4] = o1;
  }
}

// ---------------- launcher ----------------
extern "C" void kernel_launch(void* const* d_in, const int* in_sizes, int n_in,
                              void* d_out, int out_size, void* d_ws, size_t ws_size,
                              hipStream_t stream) {
  const int*   Z      = (const int*)d_in[0];
  const float* R      = (const float*)d_in[1];
  const int*   idx_i  = (const int*)d_in[2];
  const int*   idx_j  = (const int*)d_in[3];
  const float* emb    = (const float*)d_in[4];
  const float* in2f_W = (const float*)d_in[5];
  const float* in2f_b = (const float*)d_in[6];
  const float* fW1    = (const float*)d_in[7];
  const float* fb1    = (const float*)d_in[8];
  const float* fW2    = (const float*)d_in[9];
  const float* fb2    = (const float*)d_in[10];
  const float* oW1    = (const float*)d_in[11];
  const float* ob1    = (const float*)d_in[12];
  const float* oW2    = (const float*)d_in[13];
  const float* ob2    = (const float*)d_in[14];
  float* x = (float*)d_out;

  char* ws = (char*)d_ws;
  float*  d_all  = (float*) (ws + 0x000000);   // 2 MB
  int*    hist   = (int*)   (ws + 0x200000);   // 64 KB
  int*    cursor = (int*)   (ws + 0x210000);   // 64 KB
  int*    offs   = (int*)   (ws + 0x220000);   // 128 KB
  int2*   pjd    = (int2*)  (ws + 0x240000);   // 4 MB
  __half* table  = (__half*)(ws + 0x640000);   // 3 x 2050 x 128 x 2B = 1.54 MB
  __half* h_h    = (__half*)(ws + 0x800000);   // 4 MB
  float*  agg    = (float*) (ws + 0xC00000);   // 8 MB

  zero_kernel<<<64, 256, 0, stream>>>(hist, NATOMS);
  pairs_a<<<NPAIRS / 256, 256, 0, stream>>>(idx_i, idx_j, R, d_all, hist);
  scan_kernel<<<1, 1024, 0, stream>>>(hist, offs, cursor);
  pairs_b<<<NPAIRS / 256, 256, 0, stream>>>(idx_i, idx_j, d_all, cursor, pjd);
  table_kernel<<<3 * 65, 256, 0, stream>>>(fW1, fb1, fW2, fb2, table);
  embed_kernel<<<(NATOMS * 32) / 256, 256, 0, stream>>>(Z, emb, x);

  for (int l = 0; l < 3; ++l) {
    gemm_in<<<NATOMS / 64, 512, 0, stream>>>(x, in2f_W + (size_t)l * 128 * 128,
                                             in2f_b + (size_t)l * 128, h_h);
    agg_kernel<<<NATOMS / 4, 256, 0, stream>>>(pjd, offs, h_h,
                                               table + (size_t)l * TROWS * 128, agg);
    out_mlp<<<NATOMS / 64, 512, 0, stream>>>(agg, oW1 + (size_t)l * 128 * 128,
                                             ob1 + (size_t)l * 128,
                                             oW2 + (size_t)l * 128 * 128,
                                             ob2 + (size_t)l * 128, x);
  }
}

// Round 4
// 251.594 us; speedup vs baseline: 1.4384x; 1.0430x over previous
//
#include <hip/hip_runtime.h>
#include <hip/hip_bf16.h>
#include <hip/hip_fp16.h>

#define NPAIRS 524288
#define NATOMS 16384
#define TBINS  512            // lerp bins for agg table
#define TROWSG 513            // rows per layer in global table (0..512)
#define LSTRIDE 136           // halves per row in LDS (272 B, 16B-aligned)
#define CUTOFF_F 5.0f

__device__ __forceinline__ float sspf(float v) {
  float a = fabsf(v);
  return fmaxf(v, 0.0f) + log1pf(expf(-a)) - 0.69314718055994531f;
}

__device__ __forceinline__ float2 h2f(unsigned u) {
  __half2 h = *reinterpret_cast<__half2*>(&u);
  return __half22float2(h);
}

// ---------------- setup1: pairs_a (blocks 0..2047) + table gen (blocks 2048..2098) ----------------
__global__ __launch_bounds__(256) void setup1(const int* __restrict__ idx_i,
                                              const int* __restrict__ idx_j,
                                              const float* __restrict__ R,
                                              float* __restrict__ d_all,
                                              int* __restrict__ hist,
                                              const float* __restrict__ fW1,
                                              const float* __restrict__ fb1,
                                              const float* __restrict__ fW2,
                                              const float* __restrict__ fb2,
                                              __half* __restrict__ table) {
  __shared__ float W2l[64 * 128];
  __shared__ float hid[4][8][128];
  int t = threadIdx.x;

  if (blockIdx.x < 2048) {
    int p = blockIdx.x * 256 + t;
    int i = idx_i[p], j = idx_j[p];
    float dx = R[(size_t)i*3+0] - R[(size_t)j*3+0];
    float dy = R[(size_t)i*3+1] - R[(size_t)j*3+1];
    float dz = R[(size_t)i*3+2] - R[(size_t)j*3+2];
    float d = sqrtf(dx*dx + dy*dy + dz*dz);
    d_all[p] = d;
    if (d < CUTOFF_F) atomicAdd(&hist[i], 1);
    return;
  }

  int tb = blockIdx.x - 2048;          // 0..50
  int l = tb / 17;
  int tbase = (tb % 17) * 32;
  int w = t >> 6, lane = t & 63;
  const float* W1 = fW1 + (size_t)l * 20 * 128;
  const float* B1 = fb1 + (size_t)l * 128;
  const float* W2 = fW2 + (size_t)l * 128 * 128;
  const float* B2 = fb2 + (size_t)l * 128;

  const float width = CUTOFF_F / 19.0f;
  const float coeff = -0.5f / (width * width);
  const float dstep = CUTOFF_F / (float)TBINS;

  float o[8][2];
  for (int e = 0; e < 8; ++e) {
    int ti = tbase + w * 8 + e;
    float d = (float)ti * dstep;
    float h0 = B1[lane], h1 = B1[lane + 64];
    #pragma unroll
    for (int r = 0; r < 20; ++r) {
      float diff = d - (float)r * width;
      float fr = expf(coeff * diff * diff);
      h0 += fr * W1[r * 128 + lane];
      h1 += fr * W1[r * 128 + lane + 64];
    }
    hid[w][e][lane]      = sspf(h0);
    hid[w][e][lane + 64] = sspf(h1);
    o[e][0] = B2[lane];
    o[e][1] = B2[lane + 64];
  }
  for (int half = 0; half < 2; ++half) {
    __syncthreads();
    #pragma unroll
    for (int i = 0; i < 8; ++i) {
      int idx = (i * 256 + t) * 4;
      *(float4*)&W2l[idx] = *(const float4*)&W2[half * 64 * 128 + idx];
    }
    __syncthreads();
    for (int e = 0; e < 8; ++e) {
      #pragma unroll 4
      for (int g = 0; g < 64; ++g) {
        float hg = hid[w][e][half * 64 + g];
        o[e][0] += hg * W2l[g * 128 + lane];
        o[e][1] += hg * W2l[g * 128 + lane + 64];
      }
    }
  }
  for (int e = 0; e < 8; ++e) {
    int ti = tbase + w * 8 + e;
    if (ti < TROWSG) {
      float d = (float)ti * dstep;
      float fc = (d < CUTOFF_F) ? 0.5f * (cosf(d * (3.14159265358979323846f / CUTOFF_F)) + 1.0f) : 0.0f;
      size_t row = ((size_t)l * TROWSG + ti) * 128;
      table[row + lane]      = __float2half(o[e][0] * fc);
      table[row + lane + 64] = __float2half(o[e][1] * fc);
    }
  }
}

// ---------------- scan: hist -> offs/cursor ----------------
__global__ __launch_bounds__(1024) void scan_kernel(const int* __restrict__ hist,
                                                    int* __restrict__ offs,
                                                    int* __restrict__ cursor) {
  __shared__ int sums[1024];
  int t = threadIdx.x;
  int base = t * 16;
  int loc[16]; int s = 0;
  #pragma unroll
  for (int i = 0; i < 16; ++i) { loc[i] = s; s += hist[base + i]; }
  sums[t] = s;
  __syncthreads();
  for (int off = 1; off < 1024; off <<= 1) {
    int v = (t >= off) ? sums[t - off] : 0;
    __syncthreads();
    sums[t] += v;
    __syncthreads();
  }
  int excl = sums[t] - s;
  #pragma unroll
  for (int i = 0; i < 16; ++i) {
    int o = excl + loc[i];
    offs[base + i] = o;
    cursor[base + i] = o;
  }
  if (t == 1023) offs[NATOMS] = excl + s;
}

// ---------------- pb_gemm0: gemm_in layer0 (blocks 0..255, from emb gather) + pairs_b ----------------
__global__ __launch_bounds__(512) void pb_gemm0(const int* __restrict__ Z,
                                                const float* __restrict__ emb,
                                                const float* __restrict__ W,
                                                const float* __restrict__ bias,
                                                __half* __restrict__ Ch,
                                                const int* __restrict__ idx_i,
                                                const int* __restrict__ idx_j,
                                                const float* __restrict__ d_all,
                                                int* __restrict__ cursor,
                                                int2* __restrict__ pjd) {
  __shared__ float Al[64 * 128];   // 32 KB
  __shared__ float Wl[128 * 128];  // 64 KB
  int t = threadIdx.x;

  if (blockIdx.x >= 256) {
    int p = (blockIdx.x - 256) * 512 + t;
    float d = d_all[p];
    if (d < CUTOFF_F) {
      int i = idx_i[p];
      int slot = atomicAdd(&cursor[i], 1);
      pjd[slot] = make_int2(idx_j[p], __float_as_int(d));
    }
    return;
  }

  size_t rbase = (size_t)blockIdx.x * 64;
  // stage A from emb[Z[row]]
  #pragma unroll
  for (int i = 0; i < 4; ++i) {
    int idx = i * 512 + t;
    int r = idx >> 5, q = idx & 31;
    int z = Z[rbase + r];
    ((float4*)Al)[idx] = ((const float4*)emb)[(size_t)z * 32 + q];
  }
  const float4* Wg = (const float4*)W;
  #pragma unroll
  for (int i = 0; i < 8; ++i) ((float4*)Wl)[i * 512 + t] = Wg[i * 512 + t];
  __syncthreads();

  int tc = t & 31, tr = t >> 5;
  const float* Ab = &Al[(tr * 4) * 128];
  float acc[4][4];
  #pragma unroll
  for (int i = 0; i < 4; ++i) { acc[i][0] = acc[i][1] = acc[i][2] = acc[i][3] = 0.0f; }

  for (int k = 0; k < 128; k += 4) {
    float4 w0 = *(float4*)&Wl[(k + 0) * 128 + tc * 4];
    float4 w1 = *(float4*)&Wl[(k + 1) * 128 + tc * 4];
    float4 w2 = *(float4*)&Wl[(k + 2) * 128 + tc * 4];
    float4 w3 = *(float4*)&Wl[(k + 3) * 128 + tc * 4];
    #pragma unroll
    for (int i = 0; i < 4; ++i) {
      float4 av = *(float4*)&Ab[i * 128 + k];
      acc[i][0] += av.x * w0.x + av.y * w1.x + av.z * w2.x + av.w * w3.x;
      acc[i][1] += av.x * w0.y + av.y * w1.y + av.z * w2.y + av.w * w3.y;
      acc[i][2] += av.x * w0.z + av.y * w1.z + av.z * w2.z + av.w * w3.z;
      acc[i][3] += av.x * w0.w + av.y * w1.w + av.z * w2.w + av.w * w3.w;
    }
  }

  float4 bv = *(const float4*)&bias[tc * 4];
  #pragma unroll
  for (int i = 0; i < 4; ++i) {
    size_t row = rbase + tr * 4 + i;
    __half2 ha = __floats2half2_rn(acc[i][0] + bv.x, acc[i][1] + bv.y);
    __half2 hb = __floats2half2_rn(acc[i][2] + bv.z, acc[i][3] + bv.w);
    uint2 pk = make_uint2(*(unsigned*)&ha, *(unsigned*)&hb);
    *(uint2*)(Ch + row * 128 + tc * 4) = pk;
  }
}

// ---------------- agg: table in LDS, 64 atoms/block, 1024 threads ----------------
__global__ __launch_bounds__(1024) void agg_kernel(const int2* __restrict__ pjd,
                                                   const int* __restrict__ offs,
                                                   const __half* __restrict__ h,
                                                   const __half* __restrict__ table,
                                                   float* __restrict__ agg) {
  __shared__ uint4 tab4[514 * (LSTRIDE / 8)];   // 514 rows x 136 halves = 139.8 KB
  __half* tab = (__half*)tab4;
  int tid = threadIdx.x;

  // stage 513 rows, zero row 513
  const uint4* src = (const uint4*)table;
  for (int idx = tid; idx < 514 * 16; idx += 1024) {
    int r = idx >> 4, q = idx & 15;
    uint4 v = make_uint4(0, 0, 0, 0);
    if (r < TROWSG) v = src[r * 16 + q];
    tab4[r * (LSTRIDE / 8) + q] = v;
  }
  __syncthreads();

  int wid = tid >> 6, lane = tid & 63;
  int g = lane >> 4, c = lane & 15;
  const float tscale = (float)TBINS / CUTOFF_F;
  const int2 sentinel = make_int2(0, __float_as_int(CUTOFF_F));  // -> rows 512/513 (zero)

  for (int round = 0; round < 4; ++round) {
    int a = blockIdx.x * 64 + round * 16 + wid;
    int p0 = offs[a], p1 = offs[a + 1];
    int n = p1 - p0;

    float acc[8];
    #pragma unroll
    for (int q = 0; q < 8; ++q) acc[q] = 0.0f;

    int2 jdA = (g < n) ? pjd[p0 + g] : sentinel;
    int2 jdB = (g + 4 < n) ? pjd[p0 + g + 4] : sentinel;

    for (int base = 0; base < n; base += 8) {
      int nA = base + 8 + g, nB = base + 12 + g;
      int2 jdA_n = (nA < n) ? pjd[p0 + nA] : sentinel;
      int2 jdB_n = (nB < n) ? pjd[p0 + nB] : sentinel;

      float tfA = __int_as_float(jdA.y) * tscale;
      int itA = (int)tfA; float frA = tfA - (float)itA;
      float tfB = __int_as_float(jdB.y) * tscale;
      int itB = (int)tfB; float frB = tfB - (float)itB;

      const __half* tA = &tab[itA * LSTRIDE + c * 8];
      const __half* tB = &tab[itB * LSTRIDE + c * 8];
      uint4 w0A = *(const uint4*)tA;
      uint4 w1A = *(const uint4*)(tA + LSTRIDE);
      uint4 hvA = *(const uint4*)(h + (size_t)jdA.x * 128 + c * 8);
      uint4 w0B = *(const uint4*)tB;
      uint4 w1B = *(const uint4*)(tB + LSTRIDE);
      uint4 hvB = *(const uint4*)(h + (size_t)jdB.x * 128 + c * 8);

      {
        const unsigned* w0a = (const unsigned*)&w0A;
        const unsigned* w1a = (const unsigned*)&w1A;
        const unsigned* hva = (const unsigned*)&hvA;
        #pragma unroll
        for (int q = 0; q < 4; ++q) {
          float2 wa = h2f(w0a[q]), wb = h2f(w1a[q]), hh = h2f(hva[q]);
          acc[2*q]   += hh.x * fmaf(frA, wb.x - wa.x, wa.x);
          acc[2*q+1] += hh.y * fmaf(frA, wb.y - wa.y, wa.y);
        }
      }
      {
        const unsigned* w0a = (const unsigned*)&w0B;
        const unsigned* w1a = (const unsigned*)&w1B;
        const unsigned* hva = (const unsigned*)&hvB;
        #pragma unroll
        for (int q = 0; q < 4; ++q) {
          float2 wa = h2f(w0a[q]), wb = h2f(w1a[q]), hh = h2f(hva[q]);
          acc[2*q]   += hh.x * fmaf(frB, wb.x - wa.x, wa.x);
          acc[2*q+1] += hh.y * fmaf(frB, wb.y - wa.y, wa.y);
        }
      }
      jdA = jdA_n; jdB = jdB_n;
    }

    #pragma unroll
    for (int q = 0; q < 8; ++q) {
      acc[q] += __shfl_xor(acc[q], 16, 64);
      acc[q] += __shfl_xor(acc[q], 32, 64);
    }
    if (g == 0) {
      float4 o0 = make_float4(acc[0], acc[1], acc[2], acc[3]);
      float4 o1 = make_float4(acc[4], acc[5], acc[6], acc[7]);
      *(float4*)&agg[(size_t)a * 128 + c * 8]     = o0;
      *(float4*)&agg[(size_t)a * 128 + c * 8 + 4] = o1;
    }
  }
}

// ---------------- fuse: x = res + ssp(agg@oW1+b1)@oW2+b2 ; optionally h_next = x@Wn+bn ----------------
template <int FIRST, int HAS_NEXT>
__global__ __launch_bounds__(512) void fuse_kernel(const float* __restrict__ agg,
                                                   const float* __restrict__ oW1,
                                                   const float* __restrict__ ob1,
                                                   const float* __restrict__ oW2,
                                                   const float* __restrict__ ob2,
                                                   const int* __restrict__ Z,
                                                   const float* __restrict__ emb,
                                                   float* __restrict__ x,
                                                   const float* __restrict__ Wn,
                                                   const float* __restrict__ bn,
                                                   __half* __restrict__ h_next) {
  __shared__ float Al[64 * 128];   // agg tile, later x_new
  __shared__ float Wl[128 * 128];
  __shared__ float Tl[64 * 128];
  int t = threadIdx.x;
  size_t rbase = (size_t)blockIdx.x * 64;
  int tc = t & 31, tr = t >> 5;
  float acc[4][4];

  const float4* Ag = (const float4*)(agg + rbase * 128);
  #pragma unroll
  for (int i = 0; i < 4; ++i) ((float4*)Al)[i * 512 + t] = Ag[i * 512 + t];
  const float4* W1g = (const float4*)oW1;
  #pragma unroll
  for (int i = 0; i < 8; ++i) ((float4*)Wl)[i * 512 + t] = W1g[i * 512 + t];
  __syncthreads();

  // gemm1: Tl = ssp(Al @ oW1 + b1)
  {
    const float* Ab = &Al[(tr * 4) * 128];
    #pragma unroll
    for (int i = 0; i < 4; ++i) { acc[i][0] = acc[i][1] = acc[i][2] = acc[i][3] = 0.0f; }
    for (int k = 0; k < 128; k += 4) {
      float4 w0 = *(float4*)&Wl[(k + 0) * 128 + tc * 4];
      float4 w1 = *(float4*)&Wl[(k + 1) * 128 + tc * 4];
      float4 w2 = *(float4*)&Wl[(k + 2) * 128 + tc * 4];
      float4 w3 = *(float4*)&Wl[(k + 3) * 128 + tc * 4];
      #pragma unroll
      for (int i = 0; i < 4; ++i) {
        float4 av = *(float4*)&Ab[i * 128 + k];
        acc[i][0] += av.x * w0.x + av.y * w1.x + av.z * w2.x + av.w * w3.x;
        acc[i][1] += av.x * w0.y + av.y * w1.y + av.z * w2.y + av.w * w3.y;
        acc[i][2] += av.x * w0.z + av.y * w1.z + av.z * w2.z + av.w * w3.z;
        acc[i][3] += av.x * w0.w + av.y * w1.w + av.z * w2.w + av.w * w3.w;
      }
    }
    float4 bv = *(const float4*)&ob1[tc * 4];
    #pragma unroll
    for (int i = 0; i < 4; ++i) {
      float* dst = &Tl[(tr * 4 + i) * 128 + tc * 4];
      dst[0] = sspf(acc[i][0] + bv.x);
      dst[1] = sspf(acc[i][1] + bv.y);
      dst[2] = sspf(acc[i][2] + bv.z);
      dst[3] = sspf(acc[i][3] + bv.w);
    }
  }
  __syncthreads();

  const float4* W2g = (const float4*)oW2;
  #pragma unroll
  for (int i = 0; i < 8; ++i) ((float4*)Wl)[i * 512 + t] = W2g[i * 512 + t];
  __syncthreads();

  // gemm2: x_new = res + Tl @ oW2 + b2 ; write to x and Al
  {
    const float* Ab = &Tl[(tr * 4) * 128];
    #pragma unroll
    for (int i = 0; i < 4; ++i) { acc[i][0] = acc[i][1] = acc[i][2] = acc[i][3] = 0.0f; }
    for (int k = 0; k < 128; k += 4) {
      float4 w0 = *(float4*)&Wl[(k + 0) * 128 + tc * 4];
      float4 w1 = *(float4*)&Wl[(k + 1) * 128 + tc * 4];
      float4 w2 = *(float4*)&Wl[(k + 2) * 128 + tc * 4];
      float4 w3 = *(float4*)&Wl[(k + 3) * 128 + tc * 4];
      #pragma unroll
      for (int i = 0; i < 4; ++i) {
        float4 av = *(float4*)&Ab[i * 128 + k];
        acc[i][0] += av.x * w0.x + av.y * w1.x + av.z * w2.x + av.w * w3.x;
        acc[i][1] += av.x * w0.y + av.y * w1.y + av.z * w2.y + av.w * w3.y;
        acc[i][2] += av.x * w0.z + av.y * w1.z + av.z * w2.z + av.w * w3.z;
        acc[i][3] += av.x * w0.w + av.y * w1.w + av.z * w2.w + av.w * w3.w;
      }
    }
    float4 bv = *(const float4*)&ob2[tc * 4];
    #pragma unroll
    for (int i = 0; i < 4; ++i) {
      size_t row = rbase + tr * 4 + i;
      float4 res;
      if (FIRST) {
        int z = Z[row];
        res = ((const float4*)emb)[(size_t)z * 32 + tc];
      } else {
        res = *(const float4*)(x + row * 128 + tc * 4);
      }
      float4 o;
      o.x = res.x + acc[i][0] + bv.x;
      o.y = res.y + acc[i][1] + bv.y;
      o.z = res.z + acc[i][2] + bv.z;
      o.w = res.w + acc[i][3] + bv.w;
      *(float4*)(x + row * 128 + tc * 4) = o;
      *(float4*)&Al[(tr * 4 + i) * 128 + tc * 4] = o;
    }
  }

  if (HAS_NEXT) {
    __syncthreads();
    const float4* Wng = (const float4*)Wn;
    #pragma unroll
    for (int i = 0; i < 8; ++i) ((float4*)Wl)[i * 512 + t] = Wng[i * 512 + t];
    __syncthreads();

    const float* Ab = &Al[(tr * 4) * 128];
    #pragma unroll
    for (int i = 0; i < 4; ++i) { acc[i][0] = acc[i][1] = acc[i][2] = acc[i][3] = 0.0f; }
    for (int k = 0; k < 128; k += 4) {
      float4 w0 = *(float4*)&Wl[(k + 0) * 128 + tc * 4];
      float4 w1 = *(float4*)&Wl[(k + 1) * 128 + tc * 4];
      float4 w2 = *(float4*)&Wl[(k + 2) * 128 + tc * 4];
      float4 w3 = *(float4*)&Wl[(k + 3) * 128 + tc * 4];
      #pragma unroll
      for (int i = 0; i < 4; ++i) {
        float4 av = *(float4*)&Ab[i * 128 + k];
        acc[i][0] += av.x * w0.x + av.y * w1.x + av.z * w2.x + av.w * w3.x;
        acc[i][1] += av.x * w0.y + av.y * w1.y + av.z * w2.y + av.w * w3.y;
        acc[i][2] += av.x * w0.z + av.y * w1.z + av.z * w2.z + av.w * w3.z;
        acc[i][3] += av.x * w0.w + av.y * w1.w + av.z * w2.w + av.w * w3.w;
      }
    }
    float4 bv = *(const float4*)&bn[tc * 4];
    #pragma unroll
    for (int i = 0; i < 4; ++i) {
      size_t row = rbase + tr * 4 + i;
      __half2 ha = __floats2half2_rn(acc[i][0] + bv.x, acc[i][1] + bv.y);
      __half2 hb = __floats2half2_rn(acc[i][2] + bv.z, acc[i][3] + bv.w);
      uint2 pk = make_uint2(*(unsigned*)&ha, *(unsigned*)&hb);
      *(uint2*)(h_next + row * 128 + tc * 4) = pk;
    }
  }
}

// ---------------- launcher ----------------
extern "C" void kernel_launch(void* const* d_in, const int* in_sizes, int n_in,
                              void* d_out, int out_size, void* d_ws, size_t ws_size,
                              hipStream_t stream) {
  const int*   Z      = (const int*)d_in[0];
  const float* R      = (const float*)d_in[1];
  const int*   idx_i  = (const int*)d_in[2];
  const int*   idx_j  = (const int*)d_in[3];
  const float* emb    = (const float*)d_in[4];
  const float* in2f_W = (const float*)d_in[5];
  const float* in2f_b = (const float*)d_in[6];
  const float* fW1    = (const float*)d_in[7];
  const float* fb1    = (const float*)d_in[8];
  const float* fW2    = (const float*)d_in[9];
  const float* fb2    = (const float*)d_in[10];
  const float* oW1    = (const float*)d_in[11];
  const float* ob1    = (const float*)d_in[12];
  const float* oW2    = (const float*)d_in[13];
  const float* ob2    = (const float*)d_in[14];
  float* x = (float*)d_out;

  char* ws = (char*)d_ws;
  float*  d_all  = (float*) (ws + 0x000000);   // 2 MB
  int*    hist   = (int*)   (ws + 0x200000);   // 64 KB
  int*    cursor = (int*)   (ws + 0x210000);   // 64 KB
  int*    offs   = (int*)   (ws + 0x220000);   // 128 KB
  int2*   pjd    = (int2*)  (ws + 0x240000);   // 4 MB
  __half* table  = (__half*)(ws + 0x640000);   // 3 x 513 x 128 x 2B = 394 KB
  __half* h_h    = (__half*)(ws + 0x700000);   // 4 MB
  float*  aggb   = (float*) (ws + 0xB00000);   // 8 MB

  hipMemsetAsync(hist, 0, NATOMS * sizeof(int), stream);
  setup1<<<2048 + 51, 256, 0, stream>>>(idx_i, idx_j, R, d_all, hist,
                                        fW1, fb1, fW2, fb2, table);
  scan_kernel<<<1, 1024, 0, stream>>>(hist, offs, cursor);
  pb_gemm0<<<256 + NPAIRS / 512, 512, 0, stream>>>(Z, emb, in2f_W, in2f_b, h_h,
                                                   idx_i, idx_j, d_all, cursor, pjd);

  // layer 0
  agg_kernel<<<NATOMS / 64, 1024, 0, stream>>>(pjd, offs, h_h, table + 0 * TROWSG * 128, aggb);
  fuse_kernel<1, 1><<<NATOMS / 64, 512, 0, stream>>>(aggb, oW1, ob1, oW2, ob2, Z, emb, x,
                                                     in2f_W + (size_t)1 * 128 * 128,
                                                     in2f_b + (size_t)1 * 128, h_h);
  // layer 1
  agg_kernel<<<NATOMS / 64, 1024, 0, stream>>>(pjd, offs, h_h, table + 1 * TROWSG * 128, aggb);
  fuse_kernel<0, 1><<<NATOMS / 64, 512, 0, stream>>>(aggb,
                                                     oW1 + (size_t)1 * 128 * 128, ob1 + 128,
                                                     oW2 + (size_t)1 * 128 * 128, ob2 + 128,
                                                     Z, emb, x,
                                                     in2f_W + (size_t)2 * 128 * 128,
                                                     in2f_b + (size_t)2 * 128, h_h);
  // layer 2
  agg_kernel<<<NATOMS / 64, 1024, 0, stream>>>(pjd, offs, h_h, table + 2 * TROWSG * 128, aggb);
  fuse_kernel<0, 0><<<NATOMS / 64, 512, 0, stream>>>(aggb,
                                                     oW1 + (size_t)2 * 128 * 128, ob1 + 256,
                                                     oW2 + (size_t)2 * 128 * 128, ob2 + 256,
                                                     Z, emb, x, nullptr, nullptr, nullptr);
}

// Round 5
// 191.959 us; speedup vs baseline: 1.8853x; 1.3107x over previous
//
#include <hip/hip_runtime.h>
#include <hip/hip_fp16.h>

#define NPAIRS 524288
#define NATOMS 16384
#define TBINS  512            // lerp bins for agg table
#define TROWSG 513            // rows per layer in global table (0..512)
#define LSTRIDE 136           // halves per row in LDS agg table (272 B)
#define CUTOFF_F 5.0f

typedef _Float16 f16;
typedef f16 f16x2 __attribute__((ext_vector_type(2)));
typedef f16 f16x4 __attribute__((ext_vector_type(4)));
typedef f16 f16x8 __attribute__((ext_vector_type(8)));
typedef float f32x4 __attribute__((ext_vector_type(4)));

__device__ __forceinline__ float sspf(float v) {
  float a = fabsf(v);
  return fmaxf(v, 0.0f) + log1pf(expf(-a)) - 0.69314718055994531f;
}

__device__ __forceinline__ float2 h2f(unsigned u) {
  __half2 h = *reinterpret_cast<__half2*>(&u);
  return __half22float2(h);
}

// byte offset of element [row][kh] in a [*][128] f16 LDS tile, XOR-swizzled
__device__ __forceinline__ int swz(int row, int kh) {
  return (row << 8) + (((kh << 1)) ^ ((row & 7) << 4));
}

// stage W[128][128] f32 (row-major k x col) -> Wl fp16 TRANSPOSED [col][k], swizzled
__device__ __forceinline__ void stage_W(const float* __restrict__ W, char* Wl, int t) {
  int c0 = (t & 31) * 4;
  int kb = (t >> 5) * 2;
  #pragma unroll
  for (int i = 0; i < 8; ++i) {
    int k = i * 16 + kb;
    float4 a = ((const float4*)W)[k * 32 + (t & 31)];
    float4 b = ((const float4*)W)[(k + 1) * 32 + (t & 31)];
    const float* ap = (const float*)&a;
    const float* bp = (const float*)&b;
    #pragma unroll
    for (int c = 0; c < 4; ++c) {
      f16x2 p = { (f16)ap[c], (f16)bp[c] };
      *(f16x2*)(Wl + swz(c0 + c, k)) = p;
    }
  }
}

// stage A[64][128] f32 -> Al fp16 [row][k], swizzled
__device__ __forceinline__ void stage_A_f32(const float* __restrict__ A, char* Al, int t) {
  #pragma unroll
  for (int i = 0; i < 8; ++i) {
    int idx = i * 256 + t;
    int r = idx >> 5, q = idx & 31;
    float4 v = ((const float4*)A)[idx];
    f16x4 h = { (f16)v.x, (f16)v.y, (f16)v.z, (f16)v.w };
    *(f16x4*)(Al + swz(r, q * 4)) = h;
  }
}

// ================= setup1: table gen (blocks 0..194) + pairs_a =================
__global__ __launch_bounds__(256) void setup1(const int* __restrict__ idx_i,
                                              const int* __restrict__ idx_j,
                                              const float* __restrict__ R,
                                              float* __restrict__ d_all,
                                              int* __restrict__ hist,
                                              const float* __restrict__ fW1,
                                              const float* __restrict__ fb1,
                                              const float* __restrict__ fW2,
                                              const float* __restrict__ fb2,
                                              __half* __restrict__ table) {
  __shared__ float hid[8 * 128];
  int t = threadIdx.x;

  if (blockIdx.x >= 195) {
    int p = (blockIdx.x - 195) * 256 + t;
    int i = idx_i[p], j = idx_j[p];
    float dx = R[(size_t)i*3+0] - R[(size_t)j*3+0];
    float dy = R[(size_t)i*3+1] - R[(size_t)j*3+1];
    float dz = R[(size_t)i*3+2] - R[(size_t)j*3+2];
    float d = sqrtf(dx*dx + dy*dy + dz*dz);
    d_all[p] = d;
    if (d < CUTOFF_F) atomicAdd(&hist[i], 1);
    return;
  }

  int l = blockIdx.x / 65;
  int e8 = (blockIdx.x % 65) * 8;
  int e = t >> 5, q = t & 31;
  int ti = e8 + e;
  const float* W1 = fW1 + (size_t)l * 20 * 128;
  const float* B1 = fb1 + (size_t)l * 128;
  const float* W2 = fW2 + (size_t)l * 128 * 128;
  const float* B2 = fb2 + (size_t)l * 128;

  const float width = CUTOFF_F / 19.0f;
  const float coeff = -0.5f / (width * width);
  const float dstep = CUTOFF_F / (float)TBINS;
  float d = (float)ti * dstep;

  // phase A: hidden activations (this thread: entry e, dims q*4..q*4+3)
  float4 h4 = *(const float4*)&B1[q * 4];
  #pragma unroll
  for (int r = 0; r < 20; ++r) {
    float diff = d - (float)r * width;
    float fr = expf(coeff * diff * diff);
    float4 w4 = *(const float4*)&W1[r * 128 + q * 4];
    h4.x += fr * w4.x; h4.y += fr * w4.y; h4.z += fr * w4.z; h4.w += fr * w4.w;
  }
  float4 s4 = make_float4(sspf(h4.x), sspf(h4.y), sspf(h4.z), sspf(h4.w));
  *(float4*)&hid[e * 128 + q * 4] = s4;
  __syncthreads();

  // phase B: o[col4] = B2 + sum_g hid[e][g] * W2[g][col4]   (W2 streamed from L2)
  float4 o4 = *(const float4*)&B2[q * 4];
  const float4* W2g = (const float4*)W2;
  #pragma unroll 4
  for (int g = 0; g < 128; ++g) {
    float hv = hid[e * 128 + g];
    float4 w4 = W2g[g * 32 + q];
    o4.x += hv * w4.x; o4.y += hv * w4.y; o4.z += hv * w4.z; o4.w += hv * w4.w;
  }

  if (ti < TROWSG) {
    float fc = (d < CUTOFF_F) ? 0.5f * (cosf(d * (3.14159265358979323846f / CUTOFF_F)) + 1.0f) : 0.0f;
    f16x4 hv = { (f16)(o4.x * fc), (f16)(o4.y * fc), (f16)(o4.z * fc), (f16)(o4.w * fc) };
    *(f16x4*)((f16*)table + ((size_t)l * TROWSG + ti) * 128 + q * 4) = hv;
  }
}

// ================= scan: hist -> offs/cursor =================
__global__ __launch_bounds__(1024) void scan_kernel(const int* __restrict__ hist,
                                                    int* __restrict__ offs,
                                                    int* __restrict__ cursor) {
  __shared__ int sums[1024];
  int t = threadIdx.x;
  int base = t * 16;
  int loc[16]; int s = 0;
  #pragma unroll
  for (int i = 0; i < 16; ++i) { loc[i] = s; s += hist[base + i]; }
  sums[t] = s;
  __syncthreads();
  for (int off = 1; off < 1024; off <<= 1) {
    int v = (t >= off) ? sums[t - off] : 0;
    __syncthreads();
    sums[t] += v;
    __syncthreads();
  }
  int excl = sums[t] - s;
  #pragma unroll
  for (int i = 0; i < 16; ++i) {
    int o = excl + loc[i];
    offs[base + i] = o;
    cursor[base + i] = o;
  }
  if (t == 1023) offs[NATOMS] = excl + s;
}

// ================= pb_gemm0: MFMA gemm_in layer0 (blocks 0..255) + pairs_b =================
__global__ __launch_bounds__(256) void pb_gemm0(const int* __restrict__ Z,
                                                const float* __restrict__ emb,
                                                const float* __restrict__ W,
                                                const float* __restrict__ bias,
                                                __half* __restrict__ Ch,
                                                const int* __restrict__ idx_i,
                                                const int* __restrict__ idx_j,
                                                const float* __restrict__ d_all,
                                                int* __restrict__ cursor,
                                                int2* __restrict__ pjd) {
  __shared__ char smem[49152];   // A_h 16 KB + W_h 32 KB
  char* Al = smem;
  char* Wl = smem + 16384;
  int t = threadIdx.x;

  if (blockIdx.x >= 256) {
    int p = (blockIdx.x - 256) * 256 + t;
    float d = d_all[p];
    if (d < CUTOFF_F) {
      int i = idx_i[p];
      int slot = atomicAdd(&cursor[i], 1);
      pjd[slot] = make_int2(idx_j[p], __float_as_int(d));
    }
    return;
  }

  size_t rbase = (size_t)blockIdx.x * 64;
  // stage A from emb[Z[row]]
  #pragma unroll
  for (int i = 0; i < 8; ++i) {
    int idx = i * 256 + t;
    int r = idx >> 5, q = idx & 31;
    int z = Z[rbase + r];
    float4 v = ((const float4*)emb)[(size_t)z * 32 + q];
    f16x4 h = { (f16)v.x, (f16)v.y, (f16)v.z, (f16)v.w };
    *(f16x4*)(Al + swz(r, q * 4)) = h;
  }
  stage_W(W, Wl, t);
  __syncthreads();

  int w = t >> 6, lane = t & 63;
  int lo = lane & 15, hi = lane >> 4;
  f16x8 fa[4];
  #pragma unroll
  for (int s = 0; s < 4; ++s)
    fa[s] = *(f16x8*)(Al + swz(16 * w + lo, s * 32 + hi * 8));

  f16* hn = (f16*)Ch;
  #pragma unroll
  for (int cb = 0; cb < 8; ++cb) {
    f32x4 acc = {0.0f, 0.0f, 0.0f, 0.0f};
    #pragma unroll
    for (int s = 0; s < 4; ++s) {
      f16x8 fb = *(f16x8*)(Wl + swz(cb * 16 + lo, s * 32 + hi * 8));
      acc = __builtin_amdgcn_mfma_f32_16x16x32_f16(fa[s], fb, acc, 0, 0, 0);
    }
    int col = cb * 16 + lo;
    float bc = bias[col];
    #pragma unroll
    for (int j = 0; j < 4; ++j) {
      size_t rg = rbase + 16 * w + hi * 4 + j;
      hn[rg * 128 + col] = (f16)(acc[j] + bc);
    }
  }
}

// ================= agg: table in LDS, 64 atoms/block =================
__global__ __launch_bounds__(1024) void agg_kernel(const int2* __restrict__ pjd,
                                                   const int* __restrict__ offs,
                                                   const __half* __restrict__ h,
                                                   const __half* __restrict__ table,
                                                   float* __restrict__ agg) {
  __shared__ uint4 tab4[514 * (LSTRIDE / 8)];
  __half* tab = (__half*)tab4;
  int tid = threadIdx.x;

  const uint4* src = (const uint4*)table;
  for (int idx = tid; idx < 514 * 16; idx += 1024) {
    int r = idx >> 4, q = idx & 15;
    uint4 v = make_uint4(0, 0, 0, 0);
    if (r < TROWSG) v = src[r * 16 + q];
    tab4[r * (LSTRIDE / 8) + q] = v;
  }
  __syncthreads();

  int wid = tid >> 6, lane = tid & 63;
  int g = lane >> 4, c = lane & 15;
  const float tscale = (float)TBINS / CUTOFF_F;
  const int2 sentinel = make_int2(0, __float_as_int(CUTOFF_F));

  for (int round = 0; round < 4; ++round) {
    int a = blockIdx.x * 64 + round * 16 + wid;
    int p0 = offs[a], p1 = offs[a + 1];
    int n = p1 - p0;

    float acc[8];
    #pragma unroll
    for (int q2 = 0; q2 < 8; ++q2) acc[q2] = 0.0f;

    int2 jdA = (g < n) ? pjd[p0 + g] : sentinel;
    int2 jdB = (g + 4 < n) ? pjd[p0 + g + 4] : sentinel;

    for (int base = 0; base < n; base += 8) {
      int nA = base + 8 + g, nB = base + 12 + g;
      int2 jdA_n = (nA < n) ? pjd[p0 + nA] : sentinel;
      int2 jdB_n = (nB < n) ? pjd[p0 + nB] : sentinel;

      float tfA = __int_as_float(jdA.y) * tscale;
      int itA = (int)tfA; float frA = tfA - (float)itA;
      float tfB = __int_as_float(jdB.y) * tscale;
      int itB = (int)tfB; float frB = tfB - (float)itB;

      const __half* tA = &tab[itA * LSTRIDE + c * 8];
      const __half* tB = &tab[itB * LSTRIDE + c * 8];
      uint4 w0A = *(const uint4*)tA;
      uint4 w1A = *(const uint4*)(tA + LSTRIDE);
      uint4 hvA = *(const uint4*)(h + (size_t)jdA.x * 128 + c * 8);
      uint4 w0B = *(const uint4*)tB;
      uint4 w1B = *(const uint4*)(tB + LSTRIDE);
      uint4 hvB = *(const uint4*)(h + (size_t)jdB.x * 128 + c * 8);

      {
        const unsigned* w0a = (const unsigned*)&w0A;
        const unsigned* w1a = (const unsigned*)&w1A;
        const unsigned* hva = (const unsigned*)&hvA;
        #pragma unroll
        for (int q2 = 0; q2 < 4; ++q2) {
          float2 wa = h2f(w0a[q2]), wb = h2f(w1a[q2]), hh = h2f(hva[q2]);
          acc[2*q2]   += hh.x * fmaf(frA, wb.x - wa.x, wa.x);
          acc[2*q2+1] += hh.y * fmaf(frA, wb.y - wa.y, wa.y);
        }
      }
      {
        const unsigned* w0a = (const unsigned*)&w0B;
        const unsigned* w1a = (const unsigned*)&w1B;
        const unsigned* hva = (const unsigned*)&hvB;
        #pragma unroll
        for (int q2 = 0; q2 < 4; ++q2) {
          float2 wa = h2f(w0a[q2]), wb = h2f(w1a[q2]), hh = h2f(hva[q2]);
          acc[2*q2]   += hh.x * fmaf(frB, wb.x - wa.x, wa.x);
          acc[2*q2+1] += hh.y * fmaf(frB, wb.y - wa.y, wa.y);
        }
      }
      jdA = jdA_n; jdB = jdB_n;
    }

    #pragma unroll
    for (int q2 = 0; q2 < 8; ++q2) {
      acc[q2] += __shfl_xor(acc[q2], 16, 64);
      acc[q2] += __shfl_xor(acc[q2], 32, 64);
    }
    if (g == 0) {
      float4 o0 = make_float4(acc[0], acc[1], acc[2], acc[3]);
      float4 o1 = make_float4(acc[4], acc[5], acc[6], acc[7]);
      *(float4*)&agg[(size_t)a * 128 + c * 8]     = o0;
      *(float4*)&agg[(size_t)a * 128 + c * 8 + 4] = o1;
    }
  }
}

// ================= fuse: x = res + ssp(agg@oW1+b1)@oW2+b2 ; opt h_next = x@Wn+bn =================
template <int FIRST, int HAS_NEXT>
__global__ __launch_bounds__(256) void fuse_kernel(const float* __restrict__ agg,
                                                   const float* __restrict__ oW1,
                                                   const float* __restrict__ ob1,
                                                   const float* __restrict__ oW2,
                                                   const float* __restrict__ ob2,
                                                   const int* __restrict__ Z,
                                                   const float* __restrict__ emb,
                                                   float* __restrict__ x,
                                                   const float* __restrict__ Wn,
                                                   const float* __restrict__ bn,
                                                   __half* __restrict__ h_next) {
  __shared__ char smem[65536];   // A_h 16 KB | W_h 32 KB | T_h 16 KB
  char* Al = smem;
  char* Wl = smem + 16384;
  char* Tl = smem + 49152;
  int t = threadIdx.x;
  size_t rbase = (size_t)blockIdx.x * 64;
  int w = t >> 6, lane = t & 63;
  int lo = lane & 15, hi = lane >> 4;

  stage_A_f32(agg + rbase * 128, Al, t);
  stage_W(oW1, Wl, t);
  __syncthreads();

  // ---- gemm1: T = ssp(A @ oW1 + b1) ----
  {
    f16x8 fa[4];
    #pragma unroll
    for (int s = 0; s < 4; ++s)
      fa[s] = *(f16x8*)(Al + swz(16 * w + lo, s * 32 + hi * 8));
    #pragma unroll
    for (int cb = 0; cb < 8; ++cb) {
      f32x4 acc = {0.0f, 0.0f, 0.0f, 0.0f};
      #pragma unroll
      for (int s = 0; s < 4; ++s) {
        f16x8 fb = *(f16x8*)(Wl + swz(cb * 16 + lo, s * 32 + hi * 8));
        acc = __builtin_amdgcn_mfma_f32_16x16x32_f16(fa[s], fb, acc, 0, 0, 0);
      }
      int col = cb * 16 + lo;
      float bc = ob1[col];
      #pragma unroll
      for (int j = 0; j < 4; ++j) {
        int r = 16 * w + hi * 4 + j;
        *(f16*)(Tl + swz(r, col)) = (f16)sspf(acc[j] + bc);
      }
    }
  }
  __syncthreads();
  stage_W(oW2, Wl, t);
  __syncthreads();

  // ---- gemm2: x_new = res + T @ oW2 + b2 ; write x and A_h ----
  {
    // preload residual (32 values per lane)
    float res[8][4];
    if (FIRST) {
      #pragma unroll
      for (int j = 0; j < 4; ++j) {
        int z = Z[rbase + 16 * w + hi * 4 + j];
        #pragma unroll
        for (int cb = 0; cb < 8; ++cb)
          res[cb][j] = emb[(size_t)z * 128 + cb * 16 + lo];
      }
    } else {
      #pragma unroll
      for (int cb = 0; cb < 8; ++cb)
        #pragma unroll
        for (int j = 0; j < 4; ++j)
          res[cb][j] = x[(rbase + 16 * w + hi * 4 + j) * 128 + cb * 16 + lo];
    }

    f16x8 fa[4];
    #pragma unroll
    for (int s = 0; s < 4; ++s)
      fa[s] = *(f16x8*)(Tl + swz(16 * w + lo, s * 32 + hi * 8));
    #pragma unroll
    for (int cb = 0; cb < 8; ++cb) {
      f32x4 acc = {0.0f, 0.0f, 0.0f, 0.0f};
      #pragma unroll
      for (int s = 0; s < 4; ++s) {
        f16x8 fb = *(f16x8*)(Wl + swz(cb * 16 + lo, s * 32 + hi * 8));
        acc = __builtin_amdgcn_mfma_f32_16x16x32_f16(fa[s], fb, acc, 0, 0, 0);
      }
      int col = cb * 16 + lo;
      float bc = ob2[col];
      #pragma unroll
      for (int j = 0; j < 4; ++j) {
        int r = 16 * w + hi * 4 + j;
        float xn = res[cb][j] + acc[j] + bc;
        x[(rbase + r) * 128 + col] = xn;
        if (HAS_NEXT) *(f16*)(Al + swz(r, col)) = (f16)xn;
      }
    }
  }

  if (HAS_NEXT) {
    __syncthreads();
    stage_W(Wn, Wl, t);
    __syncthreads();
    f16x8 fa[4];
    #pragma unroll
    for (int s = 0; s < 4; ++s)
      fa[s] = *(f16x8*)(Al + swz(16 * w + lo, s * 32 + hi * 8));
    f16* hn = (f16*)h_next;
    #pragma unroll
    for (int cb = 0; cb < 8; ++cb) {
      f32x4 acc = {0.0f, 0.0f, 0.0f, 0.0f};
      #pragma unroll
      for (int s = 0; s < 4; ++s) {
        f16x8 fb = *(f16x8*)(Wl + swz(cb * 16 + lo, s * 32 + hi * 8));
        acc = __builtin_amdgcn_mfma_f32_16x16x32_f16(fa[s], fb, acc, 0, 0, 0);
      }
      int col = cb * 16 + lo;
      float bc = bn[col];
      #pragma unroll
      for (int j = 0; j < 4; ++j) {
        size_t rg = rbase + 16 * w + hi * 4 + j;
        hn[rg * 128 + col] = (f16)(acc[j] + bc);
      }
    }
  }
}

// ================= launcher =================
extern "C" void kernel_launch(void* const* d_in, const int* in_sizes, int n_in,
                              void* d_out, int out_size, void* d_ws, size_t ws_size,
                              hipStream_t stream) {
  const int*   Z      = (const int*)d_in[0];
  const float* R      = (const float*)d_in[1];
  const int*   idx_i  = (const int*)d_in[2];
  const int*   idx_j  = (const int*)d_in[3];
  const float* emb    = (const float*)d_in[4];
  const float* in2f_W = (const float*)d_in[5];
  const float* in2f_b = (const float*)d_in[6];
  const float* fW1    = (const float*)d_in[7];
  const float* fb1    = (const float*)d_in[8];
  const float* fW2    = (const float*)d_in[9];
  const float* fb2    = (const float*)d_in[10];
  const float* oW1    = (const float*)d_in[11];
  const float* ob1    = (const float*)d_in[12];
  const float* oW2    = (const float*)d_in[13];
  const float* ob2    = (const float*)d_in[14];
  float* x = (float*)d_out;

  char* ws = (char*)d_ws;
  float*  d_all  = (float*) (ws + 0x000000);   // 2 MB
  int*    hist   = (int*)   (ws + 0x200000);   // 64 KB
  int*    cursor = (int*)   (ws + 0x210000);   // 64 KB
  int*    offs   = (int*)   (ws + 0x220000);   // 128 KB
  int2*   pjd    = (int2*)  (ws + 0x240000);   // 4 MB
  __half* table  = (__half*)(ws + 0x640000);   // 3 x 513 x 128 x 2B
  __half* h_h    = (__half*)(ws + 0x700000);   // 4 MB
  float*  aggb   = (float*) (ws + 0xB00000);   // 8 MB

  hipMemsetAsync(hist, 0, NATOMS * sizeof(int), stream);
  setup1<<<195 + NPAIRS / 256, 256, 0, stream>>>(idx_i, idx_j, R, d_all, hist,
                                                 fW1, fb1, fW2, fb2, table);
  scan_kernel<<<1, 1024, 0, stream>>>(hist, offs, cursor);
  pb_gemm0<<<256 + NPAIRS / 256, 256, 0, stream>>>(Z, emb, in2f_W, in2f_b, h_h,
                                                   idx_i, idx_j, d_all, cursor, pjd);

  // layer 0
  agg_kernel<<<NATOMS / 64, 1024, 0, stream>>>(pjd, offs, h_h, table + 0 * TROWSG * 128, aggb);
  fuse_kernel<1, 1><<<NATOMS / 64, 256, 0, stream>>>(aggb, oW1, ob1, oW2, ob2, Z, emb, x,
                                                     in2f_W + (size_t)1 * 128 * 128,
                                                     in2f_b + (size_t)1 * 128, h_h);
  // layer 1
  agg_kernel<<<NATOMS / 64, 1024, 0, stream>>>(pjd, offs, h_h, table + 1 * TROWSG * 128, aggb);
  fuse_kernel<0, 1><<<NATOMS / 64, 256, 0, stream>>>(aggb,
                                                     oW1 + (size_t)1 * 128 * 128, ob1 + 128,
                                                     oW2 + (size_t)1 * 128 * 128, ob2 + 128,
                                                     Z, emb, x,
                                                     in2f_W + (size_t)2 * 128 * 128,
                                                     in2f_b + (size_t)2 * 128, h_h);
  // layer 2
  agg_kernel<<<NATOMS / 64, 1024, 0, stream>>>(pjd, offs, h_h, table + 2 * TROWSG * 128, aggb);
  fuse_kernel<0, 0><<<NATOMS / 64, 256, 0, stream>>>(aggb,
                                                     oW1 + (size_t)2 * 128 * 128, ob1 + 256,
                                                     oW2 + (size_t)2 * 128 * 128, ob2 + 256,
                                                     Z, emb, x, nullptr, nullptr, nullptr);
}

// Round 6
// 171.267 us; speedup vs baseline: 2.1130x; 1.1208x over previous
//
#include <hip/hip_runtime.h>
#include <hip/hip_fp16.h>

#define NPAIRS 524288
#define NATOMS 16384
#define TBINS  512            // lerp bins for agg table
#define TROWSG 513            // rows per layer in global table (0..512)
#define LSTRIDE 136           // halves per row in LDS agg table (272 B)
#define CUTOFF_F 5.0f

#define TAB_BYTES (514 * 17 * 16)     // 139,808 B
#define AL_OFF    TAB_BYTES           // fp16 A-tile (16,384 B)
#define SMEM_AF   (TAB_BYTES + 16384) // 156,192 B

typedef _Float16 f16;
typedef f16 f16x2 __attribute__((ext_vector_type(2)));
typedef f16 f16x4 __attribute__((ext_vector_type(4)));
typedef f16 f16x8 __attribute__((ext_vector_type(8)));
typedef float f32x4 __attribute__((ext_vector_type(4)));

__device__ __forceinline__ float sspf(float v) {
  float a = fabsf(v);
  return fmaxf(v, 0.0f) + log1pf(expf(-a)) - 0.69314718055994531f;
}

__device__ __forceinline__ float2 h2f(unsigned u) {
  __half2 h = *reinterpret_cast<__half2*>(&u);
  return __half22float2(h);
}

// byte offset of element [row][kh] in a [*][128] f16 LDS tile, XOR-swizzled
__device__ __forceinline__ int swz(int row, int kh) {
  return (row << 8) + (((kh << 1)) ^ ((row & 7) << 4));
}

// stage W[128][128] f32 (row-major k x col) -> Wl fp16 TRANSPOSED [col][k], swizzled (256 thr)
__device__ __forceinline__ void stage_W(const float* __restrict__ W, char* Wl, int t) {
  int c0 = (t & 31) * 4;
  int kb = (t >> 5) * 2;
  #pragma unroll
  for (int i = 0; i < 8; ++i) {
    int k = i * 16 + kb;
    float4 a = ((const float4*)W)[k * 32 + (t & 31)];
    float4 b = ((const float4*)W)[(k + 1) * 32 + (t & 31)];
    const float* ap = (const float*)&a;
    const float* bp = (const float*)&b;
    #pragma unroll
    for (int c = 0; c < 4; ++c) {
      f16x2 p = { (f16)ap[c], (f16)bp[c] };
      *(f16x2*)(Wl + swz(c0 + c, k)) = p;
    }
  }
}

// same, for 1024 threads
__device__ __forceinline__ void stage_W_1024(const float* __restrict__ W, char* Wl, int t) {
  #pragma unroll
  for (int i = 0; i < 2; ++i) {
    int idx = i * 1024 + t;     // 0..2047
    int kp = idx >> 5;          // k pair 0..63
    int q = idx & 31;
    float4 a = ((const float4*)W)[(2 * kp) * 32 + q];
    float4 b = ((const float4*)W)[(2 * kp + 1) * 32 + q];
    const float* ap = (const float*)&a;
    const float* bp = (const float*)&b;
    #pragma unroll
    for (int c = 0; c < 4; ++c) {
      f16x2 p = { (f16)ap[c], (f16)bp[c] };
      *(f16x2*)(Wl + swz(q * 4 + c, 2 * kp)) = p;
    }
  }
}

// ================= zero hist =================
__global__ __launch_bounds__(256) void zero_kernel(int* __restrict__ p) {
  p[blockIdx.x * 256 + threadIdx.x] = 0;
}

// ================= setup1: table gen (blocks 0..194) + pairs_a =================
__global__ __launch_bounds__(256) void setup1(const int* __restrict__ idx_i,
                                              const int* __restrict__ idx_j,
                                              const float* __restrict__ R,
                                              float* __restrict__ d_all,
                                              int* __restrict__ hist,
                                              const float* __restrict__ fW1,
                                              const float* __restrict__ fb1,
                                              const float* __restrict__ fW2,
                                              const float* __restrict__ fb2,
                                              __half* __restrict__ table) {
  __shared__ float hid[8 * 128];
  int t = threadIdx.x;

  if (blockIdx.x >= 195) {
    int p = (blockIdx.x - 195) * 256 + t;
    int i = idx_i[p], j = idx_j[p];
    float dx = R[(size_t)i*3+0] - R[(size_t)j*3+0];
    float dy = R[(size_t)i*3+1] - R[(size_t)j*3+1];
    float dz = R[(size_t)i*3+2] - R[(size_t)j*3+2];
    float d = sqrtf(dx*dx + dy*dy + dz*dz);
    d_all[p] = d;
    if (d < CUTOFF_F) atomicAdd(&hist[i], 1);
    return;
  }

  int l = blockIdx.x / 65;
  int e8 = (blockIdx.x % 65) * 8;
  int e = t >> 5, q = t & 31;
  int ti = e8 + e;
  const float* W1 = fW1 + (size_t)l * 20 * 128;
  const float* B1 = fb1 + (size_t)l * 128;
  const float* W2 = fW2 + (size_t)l * 128 * 128;
  const float* B2 = fb2 + (size_t)l * 128;

  const float width = CUTOFF_F / 19.0f;
  const float coeff = -0.5f / (width * width);
  const float dstep = CUTOFF_F / (float)TBINS;
  float d = (float)ti * dstep;

  float4 h4 = *(const float4*)&B1[q * 4];
  #pragma unroll
  for (int r = 0; r < 20; ++r) {
    float diff = d - (float)r * width;
    float fr = expf(coeff * diff * diff);
    float4 w4 = *(const float4*)&W1[r * 128 + q * 4];
    h4.x += fr * w4.x; h4.y += fr * w4.y; h4.z += fr * w4.z; h4.w += fr * w4.w;
  }
  float4 s4 = make_float4(sspf(h4.x), sspf(h4.y), sspf(h4.z), sspf(h4.w));
  *(float4*)&hid[e * 128 + q * 4] = s4;
  __syncthreads();

  float4 o4 = *(const float4*)&B2[q * 4];
  const float4* W2g = (const float4*)W2;
  #pragma unroll 4
  for (int g = 0; g < 128; ++g) {
    float hv = hid[e * 128 + g];
    float4 w4 = W2g[g * 32 + q];
    o4.x += hv * w4.x; o4.y += hv * w4.y; o4.z += hv * w4.z; o4.w += hv * w4.w;
  }

  if (ti < TROWSG) {
    float fc = (d < CUTOFF_F) ? 0.5f * (cosf(d * (3.14159265358979323846f / CUTOFF_F)) + 1.0f) : 0.0f;
    f16x4 hv = { (f16)(o4.x * fc), (f16)(o4.y * fc), (f16)(o4.z * fc), (f16)(o4.w * fc) };
    *(f16x4*)((f16*)table + ((size_t)l * TROWSG + ti) * 128 + q * 4) = hv;
  }
}

// ================= scan: hist -> offs/cursor =================
__global__ __launch_bounds__(1024) void scan_kernel(const int* __restrict__ hist,
                                                    int* __restrict__ offs,
                                                    int* __restrict__ cursor) {
  __shared__ int sums[1024];
  int t = threadIdx.x;
  int base = t * 16;
  int loc[16]; int s = 0;
  #pragma unroll
  for (int i = 0; i < 16; ++i) { loc[i] = s; s += hist[base + i]; }
  sums[t] = s;
  __syncthreads();
  for (int off = 1; off < 1024; off <<= 1) {
    int v = (t >= off) ? sums[t - off] : 0;
    __syncthreads();
    sums[t] += v;
    __syncthreads();
  }
  int excl = sums[t] - s;
  #pragma unroll
  for (int i = 0; i < 16; ++i) {
    int o = excl + loc[i];
    offs[base + i] = o;
    cursor[base + i] = o;
  }
  if (t == 1023) offs[NATOMS] = excl + s;
}

// ================= pb_gemm0: MFMA gemm_in layer0 (blocks 0..255) + pairs_b =================
__global__ __launch_bounds__(256) void pb_gemm0(const int* __restrict__ Z,
                                                const float* __restrict__ emb,
                                                const float* __restrict__ W,
                                                const float* __restrict__ bias,
                                                __half* __restrict__ Ch,
                                                const int* __restrict__ idx_i,
                                                const int* __restrict__ idx_j,
                                                const float* __restrict__ d_all,
                                                int* __restrict__ cursor,
                                                int2* __restrict__ pjd) {
  __shared__ char smem[49152];
  char* Al = smem;
  char* Wl = smem + 16384;
  int t = threadIdx.x;

  if (blockIdx.x >= 256) {
    int p = (blockIdx.x - 256) * 256 + t;
    float d = d_all[p];
    if (d < CUTOFF_F) {
      int i = idx_i[p];
      int slot = atomicAdd(&cursor[i], 1);
      pjd[slot] = make_int2(idx_j[p], __float_as_int(d));
    }
    return;
  }

  size_t rbase = (size_t)blockIdx.x * 64;
  #pragma unroll
  for (int i = 0; i < 8; ++i) {
    int idx = i * 256 + t;
    int r = idx >> 5, q = idx & 31;
    int z = Z[rbase + r];
    float4 v = ((const float4*)emb)[(size_t)z * 32 + q];
    f16x4 h = { (f16)v.x, (f16)v.y, (f16)v.z, (f16)v.w };
    *(f16x4*)(Al + swz(r, q * 4)) = h;
  }
  stage_W(W, Wl, t);
  __syncthreads();

  int w = t >> 6, lane = t & 63;
  int lo = lane & 15, hi = lane >> 4;
  f16x8 fa[4];
  #pragma unroll
  for (int s = 0; s < 4; ++s)
    fa[s] = *(f16x8*)(Al + swz(16 * w + lo, s * 32 + hi * 8));

  f16* hn = (f16*)Ch;
  #pragma unroll
  for (int cb = 0; cb < 8; ++cb) {
    f32x4 acc = {0.0f, 0.0f, 0.0f, 0.0f};
    #pragma unroll
    for (int s = 0; s < 4; ++s) {
      f16x8 fb = *(f16x8*)(Wl + swz(cb * 16 + lo, s * 32 + hi * 8));
      acc = __builtin_amdgcn_mfma_f32_16x16x32_f16(fa[s], fb, acc, 0, 0, 0);
    }
    int col = cb * 16 + lo;
    float bc = bias[col];
    #pragma unroll
    for (int j = 0; j < 4; ++j) {
      size_t rg = rbase + 16 * w + hi * 4 + j;
      hn[rg * 128 + col] = (f16)(acc[j] + bc);
    }
  }
}

// ================= aggfuse: agg (table in LDS) + fused output MLP (+ next in2f) =================
template <int FIRST, int HAS_NEXT>
__global__ __launch_bounds__(1024) void aggfuse(const int2* __restrict__ pjd,
                                                const int* __restrict__ offs,
                                                const __half* __restrict__ h,
                                                const __half* __restrict__ table,
                                                const float* __restrict__ oW1,
                                                const float* __restrict__ ob1,
                                                const float* __restrict__ oW2,
                                                const float* __restrict__ ob2,
                                                const int* __restrict__ Z,
                                                const float* __restrict__ emb,
                                                float* __restrict__ x,
                                                const float* __restrict__ Wn,
                                                const float* __restrict__ bn,
                                                __half* __restrict__ h_next) {
  __shared__ char smem[SMEM_AF];
  __half* tab = (__half*)smem;
  uint4*  tab4 = (uint4*)smem;
  char*   AlT = smem + AL_OFF;    // fp16 A-tile (agg results)
  char*   Wl  = smem;             // reuses table region in fuse phase
  char*   Tl  = smem + 32768;     // hidden tile in fuse phase
  int tid = threadIdx.x;
  size_t rbase = (size_t)blockIdx.x * 64;

  // ---- stage table ----
  const uint4* src = (const uint4*)table;
  for (int idx = tid; idx < 514 * 16; idx += 1024) {
    int r = idx >> 4, q = idx & 15;
    uint4 v = make_uint4(0, 0, 0, 0);
    if (r < TROWSG) v = src[r * 16 + q];
    tab4[r * (LSTRIDE / 8) + q] = v;
  }
  __syncthreads();

  // ---- agg phase: 16 waves x 4 rounds, results -> AlT (swizzled fp16) ----
  {
    int wid = tid >> 6, lane = tid & 63;
    int g = lane >> 4, c = lane & 15;
    const float tscale = (float)TBINS / CUTOFF_F;
    const int2 sentinel = make_int2(0, __float_as_int(CUTOFF_F));

    for (int round = 0; round < 4; ++round) {
      int r = round * 16 + wid;
      int a = (int)rbase + r;
      int p0 = offs[a], p1 = offs[a + 1];
      int n = p1 - p0;

      float acc[8];
      #pragma unroll
      for (int q2 = 0; q2 < 8; ++q2) acc[q2] = 0.0f;

      int2 jdA = (g < n) ? pjd[p0 + g] : sentinel;
      int2 jdB = (g + 4 < n) ? pjd[p0 + g + 4] : sentinel;

      for (int base = 0; base < n; base += 8) {
        int nA = base + 8 + g, nB = base + 12 + g;
        int2 jdA_n = (nA < n) ? pjd[p0 + nA] : sentinel;
        int2 jdB_n = (nB < n) ? pjd[p0 + nB] : sentinel;

        float tfA = __int_as_float(jdA.y) * tscale;
        int itA = (int)tfA; float frA = tfA - (float)itA;
        float tfB = __int_as_float(jdB.y) * tscale;
        int itB = (int)tfB; float frB = tfB - (float)itB;

        const __half* tA = &tab[itA * LSTRIDE + c * 8];
        const __half* tB = &tab[itB * LSTRIDE + c * 8];
        uint4 w0A = *(const uint4*)tA;
        uint4 w1A = *(const uint4*)(tA + LSTRIDE);
        uint4 hvA = *(const uint4*)(h + (size_t)jdA.x * 128 + c * 8);
        uint4 w0B = *(const uint4*)tB;
        uint4 w1B = *(const uint4*)(tB + LSTRIDE);
        uint4 hvB = *(const uint4*)(h + (size_t)jdB.x * 128 + c * 8);

        {
          const unsigned* w0a = (const unsigned*)&w0A;
          const unsigned* w1a = (const unsigned*)&w1A;
          const unsigned* hva = (const unsigned*)&hvA;
          #pragma unroll
          for (int q2 = 0; q2 < 4; ++q2) {
            float2 wa = h2f(w0a[q2]), wb = h2f(w1a[q2]), hh = h2f(hva[q2]);
            acc[2*q2]   += hh.x * fmaf(frA, wb.x - wa.x, wa.x);
            acc[2*q2+1] += hh.y * fmaf(frA, wb.y - wa.y, wa.y);
          }
        }
        {
          const unsigned* w0a = (const unsigned*)&w0B;
          const unsigned* w1a = (const unsigned*)&w1B;
          const unsigned* hva = (const unsigned*)&hvB;
          #pragma unroll
          for (int q2 = 0; q2 < 4; ++q2) {
            float2 wa = h2f(w0a[q2]), wb = h2f(w1a[q2]), hh = h2f(hva[q2]);
            acc[2*q2]   += hh.x * fmaf(frB, wb.x - wa.x, wa.x);
            acc[2*q2+1] += hh.y * fmaf(frB, wb.y - wa.y, wa.y);
          }
        }
        jdA = jdA_n; jdB = jdB_n;
      }

      #pragma unroll
      for (int q2 = 0; q2 < 8; ++q2) {
        acc[q2] += __shfl_xor(acc[q2], 16, 64);
        acc[q2] += __shfl_xor(acc[q2], 32, 64);
      }
      if (g == 0) {
        f16x8 packed;
        #pragma unroll
        for (int q2 = 0; q2 < 8; ++q2) packed[q2] = (f16)acc[q2];
        *(f16x8*)(AlT + swz(r, c * 8)) = packed;
      }
    }
  }
  __syncthreads();

  // ---- fuse phase: 8 waves compute, all threads stage ----
  stage_W_1024(oW1, Wl, tid);
  __syncthreads();

  int w = tid >> 6, lane = tid & 63;
  int lo = lane & 15, hi = lane >> 4;
  int wr = w & 3, wc = w >> 2;     // valid for w < 8
  bool active = (tid < 512);

  // gemm1: T = ssp(A @ oW1 + b1)
  if (active) {
    f16x8 fa[4];
    #pragma unroll
    for (int s = 0; s < 4; ++s)
      fa[s] = *(f16x8*)(AlT + swz(wr * 16 + lo, s * 32 + hi * 8));
    #pragma unroll
    for (int cb = 0; cb < 4; ++cb) {
      int colblk = wc * 4 + cb;
      f32x4 acc = {0.0f, 0.0f, 0.0f, 0.0f};
      #pragma unroll
      for (int s = 0; s < 4; ++s) {
        f16x8 fb = *(f16x8*)(Wl + swz(colblk * 16 + lo, s * 32 + hi * 8));
        acc = __builtin_amdgcn_mfma_f32_16x16x32_f16(fa[s], fb, acc, 0, 0, 0);
      }
      int col = colblk * 16 + lo;
      float bc = ob1[col];
      #pragma unroll
      for (int j = 0; j < 4; ++j) {
        int r = wr * 16 + hi * 4 + j;
        *(f16*)(Tl + swz(r, col)) = (f16)sspf(acc[j] + bc);
      }
    }
  }
  __syncthreads();
  stage_W_1024(oW2, Wl, tid);
  __syncthreads();

  // gemm2: x_new = res + T @ oW2 + b2 ; write x (global) and AlT (for next gemm)
  if (active) {
    float res[4][4];
    if (FIRST) {
      #pragma unroll
      for (int j = 0; j < 4; ++j) {
        int z = Z[rbase + wr * 16 + hi * 4 + j];
        #pragma unroll
        for (int cb = 0; cb < 4; ++cb)
          res[cb][j] = emb[(size_t)z * 128 + (wc * 4 + cb) * 16 + lo];
      }
    } else {
      #pragma unroll
      for (int cb = 0; cb < 4; ++cb)
        #pragma unroll
        for (int j = 0; j < 4; ++j)
          res[cb][j] = x[(rbase + wr * 16 + hi * 4 + j) * 128 + (wc * 4 + cb) * 16 + lo];
    }

    f16x8 fa[4];
    #pragma unroll
    for (int s = 0; s < 4; ++s)
      fa[s] = *(f16x8*)(Tl + swz(wr * 16 + lo, s * 32 + hi * 8));
    #pragma unroll
    for (int cb = 0; cb < 4; ++cb) {
      int colblk = wc * 4 + cb;
      f32x4 acc = {0.0f, 0.0f, 0.0f, 0.0f};
      #pragma unroll
      for (int s = 0; s < 4; ++s) {
        f16x8 fb = *(f16x8*)(Wl + swz(colblk * 16 + lo, s * 32 + hi * 8));
        acc = __builtin_amdgcn_mfma_f32_16x16x32_f16(fa[s], fb, acc, 0, 0, 0);
      }
      int col = colblk * 16 + lo;
      float bc = ob2[col];
      #pragma unroll
      for (int j = 0; j < 4; ++j) {
        int r = wr * 16 + hi * 4 + j;
        float xn = res[cb][j] + acc[j] + bc;
        x[(rbase + r) * 128 + col] = xn;
        if (HAS_NEXT) *(f16*)(AlT + swz(r, col)) = (f16)xn;
      }
    }
  }

  if (HAS_NEXT) {
    __syncthreads();
    stage_W_1024(Wn, Wl, tid);
    __syncthreads();
    if (active) {
      f16x8 fa[4];
      #pragma unroll
      for (int s = 0; s < 4; ++s)
        fa[s] = *(f16x8*)(AlT + swz(wr * 16 + lo, s * 32 + hi * 8));
      f16* hn = (f16*)h_next;
      #pragma unroll
      for (int cb = 0; cb < 4; ++cb) {
        int colblk = wc * 4 + cb;
        f32x4 acc = {0.0f, 0.0f, 0.0f, 0.0f};
        #pragma unroll
        for (int s = 0; s < 4; ++s) {
          f16x8 fb = *(f16x8*)(Wl + swz(colblk * 16 + lo, s * 32 + hi * 8));
          acc = __builtin_amdgcn_mfma_f32_16x16x32_f16(fa[s], fb, acc, 0, 0, 0);
        }
        int col = colblk * 16 + lo;
        float bc = bn[col];
        #pragma unroll
        for (int j = 0; j < 4; ++j) {
          size_t rg = rbase + wr * 16 + hi * 4 + j;
          hn[rg * 128 + col] = (f16)(acc[j] + bc);
        }
      }
    }
  }
}

// ================= launcher =================
extern "C" void kernel_launch(void* const* d_in, const int* in_sizes, int n_in,
                              void* d_out, int out_size, void* d_ws, size_t ws_size,
                              hipStream_t stream) {
  const int*   Z      = (const int*)d_in[0];
  const float* R      = (const float*)d_in[1];
  const int*   idx_i  = (const int*)d_in[2];
  const int*   idx_j  = (const int*)d_in[3];
  const float* emb    = (const float*)d_in[4];
  const float* in2f_W = (const float*)d_in[5];
  const float* in2f_b = (const float*)d_in[6];
  const float* fW1    = (const float*)d_in[7];
  const float* fb1    = (const float*)d_in[8];
  const float* fW2    = (const float*)d_in[9];
  const float* fb2    = (const float*)d_in[10];
  const float* oW1    = (const float*)d_in[11];
  const float* ob1    = (const float*)d_in[12];
  const float* oW2    = (const float*)d_in[13];
  const float* ob2    = (const float*)d_in[14];
  float* x = (float*)d_out;

  char* ws = (char*)d_ws;
  float*  d_all  = (float*) (ws + 0x000000);   // 2 MB
  int*    hist   = (int*)   (ws + 0x200000);   // 64 KB
  int*    cursor = (int*)   (ws + 0x210000);   // 64 KB
  int*    offs   = (int*)   (ws + 0x220000);   // 128 KB
  int2*   pjd    = (int2*)  (ws + 0x240000);   // 4 MB
  __half* table  = (__half*)(ws + 0x640000);   // 3 x 513 x 128 x 2B
  __half* h_h    = (__half*)(ws + 0x700000);   // 4 MB

  zero_kernel<<<NATOMS / 256, 256, 0, stream>>>(hist);
  setup1<<<195 + NPAIRS / 256, 256, 0, stream>>>(idx_i, idx_j, R, d_all, hist,
                                                 fW1, fb1, fW2, fb2, table);
  scan_kernel<<<1, 1024, 0, stream>>>(hist, offs, cursor);
  pb_gemm0<<<256 + NPAIRS / 256, 256, 0, stream>>>(Z, emb, in2f_W, in2f_b, h_h,
                                                   idx_i, idx_j, d_all, cursor, pjd);

  aggfuse<1, 1><<<NATOMS / 64, 1024, 0, stream>>>(pjd, offs, h_h,
                                                  table + 0 * TROWSG * 128,
                                                  oW1, ob1, oW2, ob2, Z, emb, x,
                                                  in2f_W + (size_t)1 * 128 * 128,
                                                  in2f_b + (size_t)1 * 128, h_h);
  aggfuse<0, 1><<<NATOMS / 64, 1024, 0, stream>>>(pjd, offs, h_h,
                                                  table + 1 * TROWSG * 128,
                                                  oW1 + (size_t)1 * 128 * 128, ob1 + 128,
                                                  oW2 + (size_t)1 * 128 * 128, ob2 + 128,
                                                  Z, emb, x,
                                                  in2f_W + (size_t)2 * 128 * 128,
                                                  in2f_b + (size_t)2 * 128, h_h);
  aggfuse<0, 0><<<NATOMS / 64, 1024, 0, stream>>>(pjd, offs, h_h,
                                                  table + 2 * TROWSG * 128,
                                                  oW1 + (size_t)2 * 128 * 128, ob1 + 256,
                                                  oW2 + (size_t)2 * 128 * 128, ob2 + 256,
                                                  Z, emb, x, nullptr, nullptr, nullptr);
}

// Round 7
// 156.929 us; speedup vs baseline: 2.3061x; 1.0914x over previous
//
#include <hip/hip_runtime.h>
#include <hip/hip_fp16.h>

#define NPAIRS 524288
#define NATOMS 16384
#define TBINS  2048
#define TROWS  2049           // rows 0..2048; row 2048 (d=5) is exactly 0
#define CUTOFF_F 5.0f

typedef _Float16 f16;
typedef f16 f16x4 __attribute__((ext_vector_type(4)));
typedef f16 f16x8 __attribute__((ext_vector_type(8)));
typedef float f32x4 __attribute__((ext_vector_type(4)));

__device__ __forceinline__ float sspf(float v) {
  float a = fabsf(v);
  return fmaxf(v, 0.0f) + log1pf(expf(-a)) - 0.69314718055994531f;
}

__device__ __forceinline__ float2 h2f(unsigned u) {
  __half2 h = *reinterpret_cast<__half2*>(&u);
  return __half22float2(h);
}

// byte offset of element [row][kh] in a [*][128] f16 LDS tile, XOR-swizzled
__device__ __forceinline__ int swz(int row, int kh) {
  return (row << 8) + ((kh << 1) ^ ((row & 7) << 4));
}

__device__ __forceinline__ uint4 ldtab(const f16* __restrict__ tabL, int v, int c) {
  return *(const uint4*)(tabL + ((unsigned)(v >> 14) << 7) + (c << 3));
}
__device__ __forceinline__ uint4 ldh(const f16* __restrict__ hin, int v, int c) {
  return *(const uint4*)(hin + ((unsigned)(v & 16383) << 7) + (c << 3));
}
__device__ __forceinline__ void dot8(float* acc, uint4 wv, uint4 hv) {
  const unsigned* wa = (const unsigned*)&wv;
  const unsigned* ha = (const unsigned*)&hv;
  #pragma unroll
  for (int q = 0; q < 4; ++q) {
    float2 w2 = h2f(wa[q]), h2v = h2f(ha[q]);
    acc[2*q]   = fmaf(w2.x, h2v.x, acc[2*q]);
    acc[2*q+1] = fmaf(w2.y, h2v.y, acc[2*q+1]);
  }
}

// ============ prep: table gen (0..194) + weight convert (195..266) + hist zero (267..330) ============
__global__ __launch_bounds__(256) void prep(const float* __restrict__ fW1,
                                            const float* __restrict__ fb1,
                                            const float* __restrict__ fW2,
                                            const float* __restrict__ fb2,
                                            f16* __restrict__ table,
                                            const float* __restrict__ in2f_W,
                                            const float* __restrict__ oW1,
                                            const float* __restrict__ oW2,
                                            f16* __restrict__ wsw,
                                            int* __restrict__ hist) {
  __shared__ float W2l[64 * 128];
  __shared__ float hid[4][8][128];
  int t = threadIdx.x;
  int bid = blockIdx.x;

  if (bid >= 267) { hist[(bid - 267) * 256 + t] = 0; return; }

  if (bid >= 195) {
    // weight convert: W[k][col] f32 -> wsw[mm] fp16 [col][k] pre-swizzled
    int mm = (bid - 195) >> 3;
    int tloc = ((bid - 195) & 7) * 256 + t;
    int col = tloc & 127, k0 = (tloc >> 7) << 3;
    const float* src = mm < 3 ? in2f_W + (size_t)mm * 16384
                     : mm < 6 ? oW1 + (size_t)(mm - 3) * 16384
                              : oW2 + (size_t)(mm - 6) * 16384;
    f16x8 v;
    #pragma unroll
    for (int kk = 0; kk < 8; ++kk) v[kk] = (f16)src[(k0 + kk) * 128 + col];
    *(f16x8*)((char*)wsw + (size_t)mm * 32768 + swz(col, k0)) = v;
    return;
  }

  // table gen: nearest-neighbor table, 32 entries/block
  int l = bid / 65, tbase = (bid % 65) * 32;
  int w = t >> 6, lane = t & 63;
  const float* W1 = fW1 + (size_t)l * 20 * 128;
  const float* B1 = fb1 + (size_t)l * 128;
  const float* W2 = fW2 + (size_t)l * 128 * 128;
  const float* B2 = fb2 + (size_t)l * 128;
  const float width = CUTOFF_F / 19.0f;
  const float coeff = -0.5f / (width * width);
  const float dstep = CUTOFF_F / (float)TBINS;

  float o[8][2];
  for (int e = 0; e < 8; ++e) {
    int ti = tbase + w * 8 + e;
    float d = (float)ti * dstep;
    float h0 = B1[lane], h1 = B1[lane + 64];
    #pragma unroll
    for (int r = 0; r < 20; ++r) {
      float diff = d - (float)r * width;
      float fr = expf(coeff * diff * diff);
      h0 += fr * W1[r * 128 + lane];
      h1 += fr * W1[r * 128 + lane + 64];
    }
    hid[w][e][lane]      = sspf(h0);
    hid[w][e][lane + 64] = sspf(h1);
    o[e][0] = B2[lane];
    o[e][1] = B2[lane + 64];
  }
  for (int half = 0; half < 2; ++half) {
    __syncthreads();
    #pragma unroll
    for (int i = 0; i < 8; ++i) {
      int idx = (i * 256 + t) * 4;
      *(float4*)&W2l[idx] = *(const float4*)&W2[half * 64 * 128 + idx];
    }
    __syncthreads();
    for (int e = 0; e < 8; ++e) {
      float s0 = o[e][0], s1 = o[e][1];
      #pragma unroll 4
      for (int g = 0; g < 64; ++g) {
        float hg = hid[w][e][half * 64 + g];
        s0 += hg * W2l[g * 128 + lane];
        s1 += hg * W2l[g * 128 + lane + 64];
      }
      o[e][0] = s0; o[e][1] = s1;
    }
  }
  for (int e = 0; e < 8; ++e) {
    int ti = tbase + w * 8 + e;
    if (ti < TROWS) {
      float d = (float)ti * dstep;
      float fc = (d < CUTOFF_F) ? 0.5f * (cosf(d * 0.62831853071795865f) + 1.0f) : 0.0f;
      size_t row = ((size_t)l * TROWS + ti) * 128;
      table[row + lane]      = (f16)(o[e][0] * fc);
      table[row + lane + 64] = (f16)(o[e][1] * fc);
    }
  }
}

// ============ pairs_a: distances -> packed (j | bin<<14), hist ============
__global__ __launch_bounds__(256) void pairs_a(const int* __restrict__ idx_i,
                                               const int* __restrict__ idx_j,
                                               const float* __restrict__ R,
                                               int* __restrict__ pd,
                                               int* __restrict__ hist) {
  int p = blockIdx.x * 256 + threadIdx.x;
  int i = idx_i[p], j = idx_j[p];
  float dx = R[(size_t)i*3+0] - R[(size_t)j*3+0];
  float dy = R[(size_t)i*3+1] - R[(size_t)j*3+1];
  float dz = R[(size_t)i*3+2] - R[(size_t)j*3+2];
  float d = sqrtf(dx*dx + dy*dy + dz*dz);
  if (d < CUTOFF_F) {
    int bin = __float2int_rn(d * ((float)TBINS / CUTOFF_F));
    pd[p] = j | (bin << 14);
    atomicAdd(&hist[i], 1);
  } else {
    pd[p] = -1;
  }
}

// ============ scan: hist -> offs/cursor ============
__global__ __launch_bounds__(1024) void scan_kernel(const int* __restrict__ hist,
                                                    int* __restrict__ offs,
                                                    int* __restrict__ cursor) {
  __shared__ int sums[1024];
  int t = threadIdx.x;
  int base = t * 16;
  int loc[16]; int s = 0;
  #pragma unroll
  for (int i = 0; i < 16; ++i) { loc[i] = s; s += hist[base + i]; }
  sums[t] = s;
  __syncthreads();
  for (int off = 1; off < 1024; off <<= 1) {
    int v = (t >= off) ? sums[t - off] : 0;
    __syncthreads();
    sums[t] += v;
    __syncthreads();
  }
  int excl = sums[t] - s;
  #pragma unroll
  for (int i = 0; i < 16; ++i) {
    int o = excl + loc[i];
    offs[base + i] = o;
    cursor[base + i] = o;
  }
  if (t == 1023) offs[NATOMS] = excl + s;
}

// ============ pb_gemm0: pairs_b (0..2047) + MFMA gemm_in layer0 (2048..2303) ============
__global__ __launch_bounds__(256) void pb_gemm0(const int* __restrict__ Z,
                                                const float* __restrict__ emb,
                                                const f16* __restrict__ Wsw,
                                                const float* __restrict__ bias,
                                                f16* __restrict__ hout,
                                                const int* __restrict__ idx_i,
                                                const int* __restrict__ pd,
                                                int* __restrict__ cursor,
                                                int* __restrict__ pjd) {
  __shared__ char smem[49152];
  char* Al = smem;
  char* Wl = smem + 16384;
  int t = threadIdx.x;

  if (blockIdx.x < 2048) {
    int p = blockIdx.x * 256 + t;
    int v = pd[p];
    if (v >= 0) {
      int i = idx_i[p];
      int slot = atomicAdd(&cursor[i], 1);
      pjd[slot] = v;
    }
    return;
  }

  size_t rbase = (size_t)(blockIdx.x - 2048) * 64;
  #pragma unroll
  for (int i = 0; i < 8; ++i) {
    int idx = i * 256 + t;
    int r = idx >> 5, q = idx & 31;
    int z = Z[rbase + r];
    float4 v = ((const float4*)emb)[(size_t)z * 32 + q];
    f16x4 h = { (f16)v.x, (f16)v.y, (f16)v.z, (f16)v.w };
    *(f16x4*)(Al + swz(r, q * 4)) = h;
  }
  #pragma unroll
  for (int i = 0; i < 8; ++i) ((uint4*)Wl)[i * 256 + t] = ((const uint4*)Wsw)[i * 256 + t];
  __syncthreads();

  int w = t >> 6, lane = t & 63;
  int lo = lane & 15, hi = lane >> 4;
  f16x8 fa[4];
  #pragma unroll
  for (int s = 0; s < 4; ++s)
    fa[s] = *(f16x8*)(Al + swz(16 * w + lo, s * 32 + hi * 8));

  #pragma unroll
  for (int cb = 0; cb < 8; ++cb) {
    f32x4 acc = {0.0f, 0.0f, 0.0f, 0.0f};
    #pragma unroll
    for (int s = 0; s < 4; ++s) {
      f16x8 fb = *(f16x8*)(Wl + swz(cb * 16 + lo, s * 32 + hi * 8));
      acc = __builtin_amdgcn_mfma_f32_16x16x32_f16(fa[s], fb, acc, 0, 0, 0);
    }
    int col = cb * 16 + lo;
    float bc = bias[col];
    #pragma unroll
    for (int j = 0; j < 4; ++j)
      hout[(rbase + 16 * w + hi * 4 + j) * 128 + col] = (f16)(acc[j] + bc);
  }
}

// ============ aggfuse: agg (L2 table, nearest) + output MLP (+ next in2f), 32 atoms/block ============
template <int FIRST, int HAS_NEXT>
__global__ __launch_bounds__(512) void aggfuse(const int* __restrict__ pjd,
                                               const int* __restrict__ offs,
                                               const f16* __restrict__ hin,
                                               const f16* __restrict__ tabL,
                                               const f16* __restrict__ W1sw,
                                               const float* __restrict__ ob1,
                                               const f16* __restrict__ W2sw,
                                               const float* __restrict__ ob2,
                                               const int* __restrict__ Z,
                                               const float* __restrict__ emb,
                                               float* __restrict__ x,
                                               const f16* __restrict__ Wnsw,
                                               const float* __restrict__ bn,
                                               f16* __restrict__ hout) {
  __shared__ char smem[49152];
  char* Wl  = smem;            // 32 KB
  char* AlT = smem + 32768;    // 8 KB (32-row fp16 A-tile)
  char* Tl  = smem + 40960;    // 8 KB
  int tid = threadIdx.x;
  int wid = tid >> 6, lane = tid & 63;
  int g = lane >> 4, c = lane & 15;
  size_t rbase = (size_t)blockIdx.x * 32;
  const int S = (TBINS << 14);   // sentinel -> zero table row, h[0]

  // ---- agg phase: 8 waves x 4 rounds, 4 pairs/group-slot, 2-deep pjd / 1-deep data prefetch ----
  for (int round = 0; round < 4; ++round) {
    int a = (int)rbase + round * 8 + wid;
    int p0 = offs[a], n = offs[a + 1] - p0;
    float acc[8];
    #pragma unroll
    for (int q = 0; q < 8; ++q) acc[q] = 0.0f;

    int vA  = (g < n)      ? pjd[p0 + g]      : S;
    int vB  = (g + 4 < n)  ? pjd[p0 + g + 4]  : S;
    int vA1 = (g + 8 < n)  ? pjd[p0 + g + 8]  : S;
    int vB1 = (g + 12 < n) ? pjd[p0 + g + 12] : S;
    uint4 wA = ldtab(tabL, vA, c), hA = ldh(hin, vA, c);
    uint4 wB = ldtab(tabL, vB, c), hB = ldh(hin, vB, c);

    for (int base = 0; base < n; base += 8) {
      int vA2 = (base + 16 + g < n) ? pjd[p0 + base + 16 + g] : S;
      int vB2 = (base + 20 + g < n) ? pjd[p0 + base + 20 + g] : S;
      uint4 wAn = ldtab(tabL, vA1, c), hAn = ldh(hin, vA1, c);
      uint4 wBn = ldtab(tabL, vB1, c), hBn = ldh(hin, vB1, c);
      dot8(acc, wA, hA);
      dot8(acc, wB, hB);
      wA = wAn; hA = hAn; wB = wBn; hB = hBn;
      vA1 = vA2; vB1 = vB2;
    }

    #pragma unroll
    for (int q = 0; q < 8; ++q) {
      acc[q] += __shfl_xor(acc[q], 16, 64);
      acc[q] += __shfl_xor(acc[q], 32, 64);
    }
    if (g == 0) {
      f16x8 pk;
      #pragma unroll
      for (int q = 0; q < 8; ++q) pk[q] = (f16)acc[q];
      *(f16x8*)(AlT + swz(round * 8 + wid, c * 8)) = pk;
    }
  }
  __syncthreads();

  // ---- fuse phase: 8 waves = 2 row-tiles x 4 col-quads ----
  #pragma unroll
  for (int i = 0; i < 4; ++i) ((uint4*)Wl)[i * 512 + tid] = ((const uint4*)W1sw)[i * 512 + tid];
  __syncthreads();

  int lo = c, hi = g;
  int wr = wid & 1, wc = wid >> 1;

  // gemm1: Tl = ssp(AlT @ oW1 + b1)
  {
    f16x8 fa[4];
    #pragma unroll
    for (int s = 0; s < 4; ++s)
      fa[s] = *(f16x8*)(AlT + swz(wr * 16 + lo, s * 32 + hi * 8));
    #pragma unroll
    for (int cb = 0; cb < 2; ++cb) {
      int colblk = wc * 2 + cb;
      f32x4 acc = {0.0f, 0.0f, 0.0f, 0.0f};
      #pragma unroll
      for (int s = 0; s < 4; ++s) {
        f16x8 fb = *(f16x8*)(Wl + swz(colblk * 16 + lo, s * 32 + hi * 8));
        acc = __builtin_amdgcn_mfma_f32_16x16x32_f16(fa[s], fb, acc, 0, 0, 0);
      }
      int col = colblk * 16 + lo;
      float bc = ob1[col];
      #pragma unroll
      for (int j = 0; j < 4; ++j)
        *(f16*)(Tl + swz(wr * 16 + hi * 4 + j, col)) = (f16)sspf(acc[j] + bc);
    }
  }
  __syncthreads();
  #pragma unroll
  for (int i = 0; i < 4; ++i) ((uint4*)Wl)[i * 512 + tid] = ((const uint4*)W2sw)[i * 512 + tid];
  __syncthreads();

  // gemm2: x_new = res + Tl @ oW2 + b2 -> x (global) and AlT (next A)
  {
    float res[2][4];
    if (FIRST) {
      #pragma unroll
      for (int j = 0; j < 4; ++j) {
        int z = Z[rbase + wr * 16 + hi * 4 + j];
        #pragma unroll
        for (int cb = 0; cb < 2; ++cb)
          res[cb][j] = emb[(size_t)z * 128 + (wc * 2 + cb) * 16 + lo];
      }
    } else {
      #pragma unroll
      for (int cb = 0; cb < 2; ++cb)
        #pragma unroll
        for (int j = 0; j < 4; ++j)
          res[cb][j] = x[(rbase + wr * 16 + hi * 4 + j) * 128 + (wc * 2 + cb) * 16 + lo];
    }

    f16x8 fa[4];
    #pragma unroll
    for (int s = 0; s < 4; ++s)
      fa[s] = *(f16x8*)(Tl + swz(wr * 16 + lo, s * 32 + hi * 8));
    #pragma unroll
    for (int cb = 0; cb < 2; ++cb) {
      int colblk = wc * 2 + cb;
      f32x4 acc = {0.0f, 0.0f, 0.0f, 0.0f};
      #pragma unroll
      for (int s = 0; s < 4; ++s) {
        f16x8 fb = *(f16x8*)(Wl + swz(colblk * 16 + lo, s * 32 + hi * 8));
        acc = __builtin_amdgcn_mfma_f32_16x16x32_f16(fa[s], fb, acc, 0, 0, 0);
      }
      int col = colblk * 16 + lo;
      float bc = ob2[col];
      #pragma unroll
      for (int j = 0; j < 4; ++j) {
        int r = wr * 16 + hi * 4 + j;
        float xn = res[cb][j] + acc[j] + bc;
        x[(rbase + r) * 128 + col] = xn;
        if (HAS_NEXT) *(f16*)(AlT + swz(r, col)) = (f16)xn;
      }
    }
  }

  if (HAS_NEXT) {
    __syncthreads();
    #pragma unroll
    for (int i = 0; i < 4; ++i) ((uint4*)Wl)[i * 512 + tid] = ((const uint4*)Wnsw)[i * 512 + tid];
    __syncthreads();
    f16x8 fa[4];
    #pragma unroll
    for (int s = 0; s < 4; ++s)
      fa[s] = *(f16x8*)(AlT + swz(wr * 16 + lo, s * 32 + hi * 8));
    #pragma unroll
    for (int cb = 0; cb < 2; ++cb) {
      int colblk = wc * 2 + cb;
      f32x4 acc = {0.0f, 0.0f, 0.0f, 0.0f};
      #pragma unroll
      for (int s = 0; s < 4; ++s) {
        f16x8 fb = *(f16x8*)(Wl + swz(colblk * 16 + lo, s * 32 + hi * 8));
        acc = __builtin_amdgcn_mfma_f32_16x16x32_f16(fa[s], fb, acc, 0, 0, 0);
      }
      int col = colblk * 16 + lo;
      float bc = bn[col];
      #pragma unroll
      for (int j = 0; j < 4; ++j)
        hout[(rbase + wr * 16 + hi * 4 + j) * 128 + col] = (f16)(acc[j] + bc);
    }
  }
}

// ============ launcher ============
extern "C" void kernel_launch(void* const* d_in, const int* in_sizes, int n_in,
                              void* d_out, int out_size, void* d_ws, size_t ws_size,
                              hipStream_t stream) {
  const int*   Z      = (const int*)d_in[0];
  const float* R      = (const float*)d_in[1];
  const int*   idx_i  = (const int*)d_in[2];
  const int*   idx_j  = (const int*)d_in[3];
  const float* emb    = (const float*)d_in[4];
  const float* in2f_W = (const float*)d_in[5];
  const float* in2f_b = (const float*)d_in[6];
  const float* fW1    = (const float*)d_in[7];
  const float* fb1    = (const float*)d_in[8];
  const float* fW2    = (const float*)d_in[9];
  const float* fb2    = (const float*)d_in[10];
  const float* oW1    = (const float*)d_in[11];
  const float* ob1    = (const float*)d_in[12];
  const float* oW2    = (const float*)d_in[13];
  const float* ob2    = (const float*)d_in[14];
  float* x = (float*)d_out;

  char* ws = (char*)d_ws;
  int*  pd     = (int*) (ws + 0x000000);   // 2 MB
  int*  hist   = (int*) (ws + 0x200000);   // 64 KB
  int*  cursor = (int*) (ws + 0x210000);   // 64 KB
  int*  offs   = (int*) (ws + 0x220000);   // 64 KB + 4
  int*  pjd    = (int*) (ws + 0x240000);   // 2 MB
  f16*  table  = (f16*) (ws + 0x440000);   // 3 x 2049 x 128 x 2B = 1.5 MB
  f16*  h0     = (f16*) (ws + 0x600000);   // 4 MB
  f16*  h1     = (f16*) (ws + 0xA00000);   // 4 MB
  f16*  wsw    = (f16*) (ws + 0xE00000);   // 9 x 32 KB

  prep<<<331, 256, 0, stream>>>(fW1, fb1, fW2, fb2, table, in2f_W, oW1, oW2, wsw, hist);
  pairs_a<<<NPAIRS / 256, 256, 0, stream>>>(idx_i, idx_j, R, pd, hist);
  scan_kernel<<<1, 1024, 0, stream>>>(hist, offs, cursor);
  pb_gemm0<<<2048 + 256, 256, 0, stream>>>(Z, emb, wsw, in2f_b, h0,
                                           idx_i, pd, cursor, pjd);

  aggfuse<1, 1><<<NATOMS / 32, 512, 0, stream>>>(pjd, offs, h0, table + 0 * (size_t)TROWS * 128,
                                                 wsw + 3 * 16384, ob1,
                                                 wsw + 6 * 16384, ob2,
                                                 Z, emb, x,
                                                 wsw + 1 * 16384, in2f_b + 128, h1);
  aggfuse<0, 1><<<NATOMS / 32, 512, 0, stream>>>(pjd, offs, h1, table + 1 * (size_t)TROWS * 128,
                                                 wsw + 4 * 16384, ob1 + 128,
                                                 wsw + 7 * 16384, ob2 + 128,
                                                 Z, emb, x,
                                                 wsw + 2 * 16384, in2f_b + 256, h0);
  aggfuse<0, 0><<<NATOMS / 32, 512, 0, stream>>>(pjd, offs, h0, table + 2 * (size_t)TROWS * 128,
                                                 wsw + 5 * 16384, ob1 + 256,
                                                 wsw + 8 * 16384, ob2 + 256,
                                                 Z, emb, x, nullptr, nullptr, nullptr);
}

// Round 8
// 150.614 us; speedup vs baseline: 2.4028x; 1.0419x over previous
//
#include <hip/hip_runtime.h>
#include <hip/hip_fp16.h>

#define NPAIRS 524288
#define NATOMS 16384
#define TBINS  2048
#define TROWS  2049           // rows 0..2048; row 2048 (d=5) is exactly 0
#define CUTOFF_F 5.0f

typedef _Float16 f16;
typedef f16 f16x4 __attribute__((ext_vector_type(4)));
typedef f16 f16x8 __attribute__((ext_vector_type(8)));
typedef float f32x4 __attribute__((ext_vector_type(4)));

__device__ __forceinline__ float sspf(float v) {
  float a = fabsf(v);
  return fmaxf(v, 0.0f) + log1pf(expf(-a)) - 0.69314718055994531f;
}

// byte offset of element [row][kh] in a [*][128] f16 LDS tile, XOR-swizzled
__device__ __forceinline__ int swz(int row, int kh) {
  return (row << 8) + ((kh << 1) ^ ((row & 7) << 4));
}

__device__ __forceinline__ uint4 ldtab(const f16* __restrict__ tabL, int v, int c) {
  return *(const uint4*)(tabL + ((unsigned)(v >> 14) << 7) + (c << 3));
}
__device__ __forceinline__ uint4 ldh(const f16* __restrict__ hin, int v, int c) {
  return *(const uint4*)(hin + ((unsigned)(v & 16383) << 7) + (c << 3));
}
// f32 += f16*f16 via v_fma_mix_f32 pattern (fpext+fma)
__device__ __forceinline__ void dot8(float* acc, uint4 wv, uint4 hv) {
  const __half* wp = (const __half*)&wv;
  const __half* hp = (const __half*)&hv;
  #pragma unroll
  for (int q = 0; q < 8; ++q)
    acc[q] = fmaf(__half2float(wp[q]), __half2float(hp[q]), acc[q]);
}

// ============ prep: wide table gen (0..770) + weight convert (771..842) + hist zero (843..906) ============
__global__ __launch_bounds__(256) void prep(const float* __restrict__ fW1,
                                            const float* __restrict__ fb1,
                                            const float* __restrict__ fW2,
                                            const float* __restrict__ fb2,
                                            f16* __restrict__ table,
                                            const float* __restrict__ in2f_W,
                                            const float* __restrict__ oW1,
                                            const float* __restrict__ oW2,
                                            f16* __restrict__ wsw,
                                            int* __restrict__ hist) {
  __shared__ float hid[8 * 128];
  int t = threadIdx.x;
  int bid = blockIdx.x;

  if (bid >= 843) { hist[(bid - 843) * 256 + t] = 0; return; }

  if (bid >= 771) {
    // weight convert: W[k][col] f32 -> wsw[mm] fp16 [col][k] pre-swizzled
    int bid2 = bid - 771;
    int mm = bid2 >> 3;
    int tloc = (bid2 & 7) * 256 + t;
    int col = tloc & 127, k0 = (tloc >> 7) << 3;
    const float* src = mm < 3 ? in2f_W + (size_t)mm * 16384
                     : mm < 6 ? oW1 + (size_t)(mm - 3) * 16384
                              : oW2 + (size_t)(mm - 6) * 16384;
    f16x8 v;
    #pragma unroll
    for (int kk = 0; kk < 8; ++kk) v[kk] = (f16)src[(k0 + kk) * 128 + col];
    *(f16x8*)((char*)wsw + (size_t)mm * 32768 + swz(col, k0)) = v;
    return;
  }

  // wide table gen: 8 entries per block, thread = (entry e, 4 cols at q*4)
  int l = bid / 257, rem = bid % 257;
  int e = t >> 5, q = t & 31;
  int ti = rem * 8 + e;
  const float* W1 = fW1 + (size_t)l * 20 * 128;
  const float* B1 = fb1 + (size_t)l * 128;
  const float* W2 = fW2 + (size_t)l * 128 * 128;
  const float* B2 = fb2 + (size_t)l * 128;

  const float width = CUTOFF_F / 19.0f;
  const float coeff = -0.5f / (width * width);
  const float dstep = CUTOFF_F / (float)TBINS;
  float d = (float)ti * dstep;

  float4 h4 = *(const float4*)&B1[q * 4];
  #pragma unroll
  for (int r = 0; r < 20; ++r) {
    float diff = d - (float)r * width;
    float fr = expf(coeff * diff * diff);
    float4 w4 = *(const float4*)&W1[r * 128 + q * 4];
    h4.x += fr * w4.x; h4.y += fr * w4.y; h4.z += fr * w4.z; h4.w += fr * w4.w;
  }
  *(float4*)&hid[e * 128 + q * 4] =
      make_float4(sspf(h4.x), sspf(h4.y), sspf(h4.z), sspf(h4.w));
  __syncthreads();

  float4 o4 = *(const float4*)&B2[q * 4];
  const float4* W2g = (const float4*)W2;
  #pragma unroll 4
  for (int g = 0; g < 128; ++g) {
    float hv = hid[e * 128 + g];
    float4 w4 = W2g[g * 32 + q];
    o4.x += hv * w4.x; o4.y += hv * w4.y; o4.z += hv * w4.z; o4.w += hv * w4.w;
  }

  if (ti < TROWS) {
    float fc = (d < CUTOFF_F) ? 0.5f * (cosf(d * 0.62831853071795865f) + 1.0f) : 0.0f;
    f16x4 hv = { (f16)(o4.x * fc), (f16)(o4.y * fc), (f16)(o4.z * fc), (f16)(o4.w * fc) };
    *(f16x4*)((f16*)table + ((size_t)l * TROWS + ti) * 128 + q * 4) = hv;
  }
}

// ============ pairs_a: distances -> packed (j | bin<<14), hist ============
__global__ __launch_bounds__(256) void pairs_a(const int* __restrict__ idx_i,
                                               const int* __restrict__ idx_j,
                                               const float* __restrict__ R,
                                               int* __restrict__ pd,
                                               int* __restrict__ hist) {
  int p = blockIdx.x * 256 + threadIdx.x;
  int i = idx_i[p], j = idx_j[p];
  float dx = R[(size_t)i*3+0] - R[(size_t)j*3+0];
  float dy = R[(size_t)i*3+1] - R[(size_t)j*3+1];
  float dz = R[(size_t)i*3+2] - R[(size_t)j*3+2];
  float d = sqrtf(dx*dx + dy*dy + dz*dz);
  if (d < CUTOFF_F) {
    int bin = __float2int_rn(d * ((float)TBINS / CUTOFF_F));
    pd[p] = j | (bin << 14);
    atomicAdd(&hist[i], 1);
  } else {
    pd[p] = -1;
  }
}

// ============ scan: hist -> offs/cursor ============
__global__ __launch_bounds__(1024) void scan_kernel(const int* __restrict__ hist,
                                                    int* __restrict__ offs,
                                                    int* __restrict__ cursor) {
  __shared__ int sums[1024];
  int t = threadIdx.x;
  int base = t * 16;
  int loc[16]; int s = 0;
  #pragma unroll
  for (int i = 0; i < 16; ++i) { loc[i] = s; s += hist[base + i]; }
  sums[t] = s;
  __syncthreads();
  for (int off = 1; off < 1024; off <<= 1) {
    int v = (t >= off) ? sums[t - off] : 0;
    __syncthreads();
    sums[t] += v;
    __syncthreads();
  }
  int excl = sums[t] - s;
  #pragma unroll
  for (int i = 0; i < 16; ++i) {
    int o = excl + loc[i];
    offs[base + i] = o;
    cursor[base + i] = o;
  }
  if (t == 1023) offs[NATOMS] = excl + s;
}

// ============ pb_gemm0: pairs_b (0..2047) + MFMA gemm_in layer0 (2048..2303) ============
__global__ __launch_bounds__(256) void pb_gemm0(const int* __restrict__ Z,
                                                const float* __restrict__ emb,
                                                const f16* __restrict__ Wsw,
                                                const float* __restrict__ bias,
                                                f16* __restrict__ hout,
                                                const int* __restrict__ idx_i,
                                                const int* __restrict__ pd,
                                                int* __restrict__ cursor,
                                                int* __restrict__ pjd) {
  __shared__ char smem[49152];
  char* Al = smem;
  char* Wl = smem + 16384;
  int t = threadIdx.x;

  if (blockIdx.x < 2048) {
    int p = blockIdx.x * 256 + t;
    int v = pd[p];
    if (v >= 0) {
      int i = idx_i[p];
      int slot = atomicAdd(&cursor[i], 1);
      pjd[slot] = v;
    }
    return;
  }

  size_t rbase = (size_t)(blockIdx.x - 2048) * 64;
  #pragma unroll
  for (int i = 0; i < 8; ++i) {
    int idx = i * 256 + t;
    int r = idx >> 5, q = idx & 31;
    int z = Z[rbase + r];
    float4 v = ((const float4*)emb)[(size_t)z * 32 + q];
    f16x4 h = { (f16)v.x, (f16)v.y, (f16)v.z, (f16)v.w };
    *(f16x4*)(Al + swz(r, q * 4)) = h;
  }
  #pragma unroll
  for (int i = 0; i < 8; ++i) ((uint4*)Wl)[i * 256 + t] = ((const uint4*)Wsw)[i * 256 + t];
  __syncthreads();

  int w = t >> 6, lane = t & 63;
  int lo = lane & 15, hi = lane >> 4;
  f16x8 fa[4];
  #pragma unroll
  for (int s = 0; s < 4; ++s)
    fa[s] = *(f16x8*)(Al + swz(16 * w + lo, s * 32 + hi * 8));

  #pragma unroll
  for (int cb = 0; cb < 8; ++cb) {
    f32x4 acc = {0.0f, 0.0f, 0.0f, 0.0f};
    #pragma unroll
    for (int s = 0; s < 4; ++s) {
      f16x8 fb = *(f16x8*)(Wl + swz(cb * 16 + lo, s * 32 + hi * 8));
      acc = __builtin_amdgcn_mfma_f32_16x16x32_f16(fa[s], fb, acc, 0, 0, 0);
    }
    int col = cb * 16 + lo;
    float bc = bias[col];
    #pragma unroll
    for (int j = 0; j < 4; ++j)
      hout[(rbase + 16 * w + hi * 4 + j) * 128 + col] = (f16)(acc[j] + bc);
  }
}

// ============ aggfuse: agg (1 atom per 16-lane slot) + output MLP (+ next in2f), 32 atoms/block ============
template <int FIRST, int HAS_NEXT>
__global__ __launch_bounds__(512, 4) void aggfuse(const int* __restrict__ pjd,
                                                  const int* __restrict__ offs,
                                                  const f16* __restrict__ hin,
                                                  const f16* __restrict__ tabL,
                                                  const f16* __restrict__ W1sw,
                                                  const float* __restrict__ ob1,
                                                  const f16* __restrict__ W2sw,
                                                  const float* __restrict__ ob2,
                                                  const int* __restrict__ Z,
                                                  const float* __restrict__ emb,
                                                  float* __restrict__ x,
                                                  const f16* __restrict__ Wnsw,
                                                  const float* __restrict__ bn,
                                                  f16* __restrict__ hout) {
  __shared__ char smem[49152];
  char* Wl  = smem;            // 32 KB
  char* AlT = smem + 32768;    // 8 KB (32-row fp16 A-tile)
  char* Tl  = smem + 40960;    // 8 KB
  int tid = threadIdx.x;
  int wv = tid >> 6, lane = tid & 63;
  int s = lane >> 4, c = lane & 15;
  size_t rbase = (size_t)blockIdx.x * 32;
  const int S = (TBINS << 14);   // sentinel -> zero table row, h[0]

  // ---- agg phase: wave = 4 independent atoms (one per slot), 2 pair-chains each ----
  {
    int row = wv * 4 + s;
    int a = (int)rbase + row;
    int p0 = offs[a];
    int n  = offs[a + 1] - p0;

    int iters = (n + 1) >> 1;
    int m = iters;
    m = max(m, __shfl_xor(m, 16, 64));
    m = max(m, __shfl_xor(m, 32, 64));

    float accA[8], accB[8];
    #pragma unroll
    for (int q = 0; q < 8; ++q) { accA[q] = 0.0f; accB[q] = 0.0f; }

    int vA  = (0 < n) ? pjd[p0]     : S;
    int vB  = (1 < n) ? pjd[p0 + 1] : S;
    int vA1 = (2 < n) ? pjd[p0 + 2] : S;
    int vB1 = (3 < n) ? pjd[p0 + 3] : S;
    uint4 wA = ldtab(tabL, vA, c), hA = ldh(hin, vA, c);
    uint4 wB = ldtab(tabL, vB, c), hB = ldh(hin, vB, c);

    for (int it = 0; it < m; ++it) {
      int k2 = 2 * it + 4;
      int vA2 = (k2 < n)     ? pjd[p0 + k2]     : S;
      int vB2 = (k2 + 1 < n) ? pjd[p0 + k2 + 1] : S;
      uint4 wAn = ldtab(tabL, vA1, c), hAn = ldh(hin, vA1, c);
      uint4 wBn = ldtab(tabL, vB1, c), hBn = ldh(hin, vB1, c);
      dot8(accA, wA, hA);
      dot8(accB, wB, hB);
      wA = wAn; hA = hAn; wB = wBn; hB = hBn;
      vA1 = vA2; vB1 = vB2;
    }

    f16x8 pk;
    #pragma unroll
    for (int q = 0; q < 8; ++q) pk[q] = (f16)(accA[q] + accB[q]);
    *(f16x8*)(AlT + swz(row, c * 8)) = pk;
  }
  __syncthreads();

  // ---- fuse phase: 8 waves = 2 row-tiles x 4 col-quads ----
  #pragma unroll
  for (int i = 0; i < 4; ++i) ((uint4*)Wl)[i * 512 + tid] = ((const uint4*)W1sw)[i * 512 + tid];
  __syncthreads();

  int lo = c, hi = s;
  int wr = wv & 1, wc = wv >> 1;

  // gemm1: Tl = ssp(AlT @ oW1 + b1)
  {
    f16x8 fa[4];
    #pragma unroll
    for (int ss = 0; ss < 4; ++ss)
      fa[ss] = *(f16x8*)(AlT + swz(wr * 16 + lo, ss * 32 + hi * 8));
    #pragma unroll
    for (int cb = 0; cb < 2; ++cb) {
      int colblk = wc * 2 + cb;
      f32x4 acc = {0.0f, 0.0f, 0.0f, 0.0f};
      #pragma unroll
      for (int ss = 0; ss < 4; ++ss) {
        f16x8 fb = *(f16x8*)(Wl + swz(colblk * 16 + lo, ss * 32 + hi * 8));
        acc = __builtin_amdgcn_mfma_f32_16x16x32_f16(fa[ss], fb, acc, 0, 0, 0);
      }
      int col = colblk * 16 + lo;
      float bc = ob1[col];
      #pragma unroll
      for (int j = 0; j < 4; ++j)
        *(f16*)(Tl + swz(wr * 16 + hi * 4 + j, col)) = (f16)sspf(acc[j] + bc);
    }
  }
  __syncthreads();
  #pragma unroll
  for (int i = 0; i < 4; ++i) ((uint4*)Wl)[i * 512 + tid] = ((const uint4*)W2sw)[i * 512 + tid];
  __syncthreads();

  // gemm2: x_new = res + Tl @ oW2 + b2 -> x (global) and AlT (next A)
  {
    float res[2][4];
    if (FIRST) {
      #pragma unroll
      for (int j = 0; j < 4; ++j) {
        int z = Z[rbase + wr * 16 + hi * 4 + j];
        #pragma unroll
        for (int cb = 0; cb < 2; ++cb)
          res[cb][j] = emb[(size_t)z * 128 + (wc * 2 + cb) * 16 + lo];
      }
    } else {
      #pragma unroll
      for (int cb = 0; cb < 2; ++cb)
        #pragma unroll
        for (int j = 0; j < 4; ++j)
          res[cb][j] = x[(rbase + wr * 16 + hi * 4 + j) * 128 + (wc * 2 + cb) * 16 + lo];
    }

    f16x8 fa[4];
    #pragma unroll
    for (int ss = 0; ss < 4; ++ss)
      fa[ss] = *(f16x8*)(Tl + swz(wr * 16 + lo, ss * 32 + hi * 8));
    #pragma unroll
    for (int cb = 0; cb < 2; ++cb) {
      int colblk = wc * 2 + cb;
      f32x4 acc = {0.0f, 0.0f, 0.0f, 0.0f};
      #pragma unroll
      for (int ss = 0; ss < 4; ++ss) {
        f16x8 fb = *(f16x8*)(Wl + swz(colblk * 16 + lo, ss * 32 + hi * 8));
        acc = __builtin_amdgcn_mfma_f32_16x16x32_f16(fa[ss], fb, acc, 0, 0, 0);
      }
      int col = colblk * 16 + lo;
      float bc = ob2[col];
      #pragma unroll
      for (int j = 0; j < 4; ++j) {
        int r = wr * 16 + hi * 4 + j;
        float xn = res[cb][j] + acc[j] + bc;
        x[(rbase + r) * 128 + col] = xn;
        if (HAS_NEXT) *(f16*)(AlT + swz(r, col)) = (f16)xn;
      }
    }
  }

  if (HAS_NEXT) {
    __syncthreads();
    #pragma unroll
    for (int i = 0; i < 4; ++i) ((uint4*)Wl)[i * 512 + tid] = ((const uint4*)Wnsw)[i * 512 + tid];
    __syncthreads();
    f16x8 fa[4];
    #pragma unroll
    for (int ss = 0; ss < 4; ++ss)
      fa[ss] = *(f16x8*)(AlT + swz(wr * 16 + lo, ss * 32 + hi * 8));
    #pragma unroll
    for (int cb = 0; cb < 2; ++cb) {
      int colblk = wc * 2 + cb;
      f32x4 acc = {0.0f, 0.0f, 0.0f, 0.0f};
      #pragma unroll
      for (int ss = 0; ss < 4; ++ss) {
        f16x8 fb = *(f16x8*)(Wl + swz(colblk * 16 + lo, ss * 32 + hi * 8));
        acc = __builtin_amdgcn_mfma_f32_16x16x32_f16(fa[ss], fb, acc, 0, 0, 0);
      }
      int col = colblk * 16 + lo;
      float bc = bn[col];
      #pragma unroll
      for (int j = 0; j < 4; ++j)
        hout[(rbase + wr * 16 + hi * 4 + j) * 128 + col] = (f16)(acc[j] + bc);
    }
  }
}

// ============ launcher ============
extern "C" void kernel_launch(void* const* d_in, const int* in_sizes, int n_in,
                              void* d_out, int out_size, void* d_ws, size_t ws_size,
                              hipStream_t stream) {
  const int*   Z      = (const int*)d_in[0];
  const float* R      = (const float*)d_in[1];
  const int*   idx_i  = (const int*)d_in[2];
  const int*   idx_j  = (const int*)d_in[3];
  const float* emb    = (const float*)d_in[4];
  const float* in2f_W = (const float*)d_in[5];
  const float* in2f_b = (const float*)d_in[6];
  const float* fW1    = (const float*)d_in[7];
  const float* fb1    = (const float*)d_in[8];
  const float* fW2    = (const float*)d_in[9];
  const float* fb2    = (const float*)d_in[10];
  const float* oW1    = (const float*)d_in[11];
  const float* ob1    = (const float*)d_in[12];
  const float* oW2    = (const float*)d_in[13];
  const float* ob2    = (const float*)d_in[14];
  float* x = (float*)d_out;

  char* ws = (char*)d_ws;
  int*  pd     = (int*) (ws + 0x000000);   // 2 MB
  int*  hist   = (int*) (ws + 0x200000);   // 64 KB
  int*  cursor = (int*) (ws + 0x210000);   // 64 KB
  int*  offs   = (int*) (ws + 0x220000);   // 64 KB + 4
  int*  pjd    = (int*) (ws + 0x240000);   // 2 MB
  f16*  table  = (f16*) (ws + 0x440000);   // 3 x 2049 x 128 x 2B = 1.5 MB
  f16*  h0     = (f16*) (ws + 0x600000);   // 4 MB
  f16*  h1     = (f16*) (ws + 0xA00000);   // 4 MB
  f16*  wsw    = (f16*) (ws + 0xE00000);   // 9 x 32 KB

  prep<<<907, 256, 0, stream>>>(fW1, fb1, fW2, fb2, table, in2f_W, oW1, oW2, wsw, hist);
  pairs_a<<<NPAIRS / 256, 256, 0, stream>>>(idx_i, idx_j, R, pd, hist);
  scan_kernel<<<1, 1024, 0, stream>>>(hist, offs, cursor);
  pb_gemm0<<<2048 + 256, 256, 0, stream>>>(Z, emb, wsw, in2f_b, h0,
                                           idx_i, pd, cursor, pjd);

  aggfuse<1, 1><<<NATOMS / 32, 512, 0, stream>>>(pjd, offs, h0, table + 0 * (size_t)TROWS * 128,
                                                 wsw + 3 * 16384, ob1,
                                                 wsw + 6 * 16384, ob2,
                                                 Z, emb, x,
                                                 wsw + 1 * 16384, in2f_b + 128, h1);
  aggfuse<0, 1><<<NATOMS / 32, 512, 0, stream>>>(pjd, offs, h1, table + 1 * (size_t)TROWS * 128,
                                                 wsw + 4 * 16384, ob1 + 128,
                                                 wsw + 7 * 16384, ob2 + 128,
                                                 Z, emb, x,
                                                 wsw + 2 * 16384, in2f_b + 256, h0);
  aggfuse<0, 0><<<NATOMS / 32, 512, 0, stream>>>(pjd, offs, h0, table + 2 * (size_t)TROWS * 128,
                                                 wsw + 5 * 16384, ob1 + 256,
                                                 wsw + 8 * 16384, ob2 + 256,
                                                 Z, emb, x, nullptr, nullptr, nullptr);
}

// Round 9
// 120.434 us; speedup vs baseline: 3.0049x; 1.2506x over previous
//
#include <hip/hip_runtime.h>
#include <hip/hip_fp16.h>

#define NPAIRS 524288
#define NATOMS 16384
#define TBINS  2048
#define TROWS  2049           // rows 0..2048; row 2048 (d=5) is exactly 0
#define CAP    80             // max stored neighbors per atom (Poisson(~20) -> safe)
#define CUTOFF_F 5.0f

typedef _Float16 f16;
typedef f16 f16x4 __attribute__((ext_vector_type(4)));
typedef f16 f16x8 __attribute__((ext_vector_type(8)));
typedef float f32x4 __attribute__((ext_vector_type(4)));

__device__ __forceinline__ float sspf(float v) {
  float a = fabsf(v);
  return fmaxf(v, 0.0f) + log1pf(expf(-a)) - 0.69314718055994531f;
}

// full-K fp16 tile [rows][128], XOR-swizzled, row stride 256 B
__device__ __forceinline__ int swz(int row, int kh) {
  return (row << 8) + ((kh << 1) ^ ((row & 7) << 4));
}
// half-K fp16 W tile [col][64], row stride 128 B
__device__ __forceinline__ int swzW(int col, int kh) {
  return (col << 7) + ((kh << 1) ^ ((col & 7) << 4));
}

__device__ __forceinline__ uint4 ldtab(const f16* __restrict__ tabL, int v, int c) {
  return *(const uint4*)(tabL + ((unsigned)(v >> 14) << 7) + (c << 3));
}
__device__ __forceinline__ uint4 ldh(const f16* __restrict__ hin, int v, int c) {
  return *(const uint4*)(hin + ((unsigned)(v & 16383) << 7) + (c << 3));
}
__device__ __forceinline__ void dot8(float* acc, uint4 wv, uint4 hv) {
  const __half* wp = (const __half*)&wv;
  const __half* hp = (const __half*)&hv;
  #pragma unroll
  for (int q = 0; q < 8; ++q)
    acc[q] = fmaf(__half2float(wp[q]), __half2float(hp[q]), acc[q]);
}

// ============ prep: table gen (0..770) + weight convert (771..842) + cursor zero (843..906) ============
__global__ __launch_bounds__(256) void prep(const float* __restrict__ fW1,
                                            const float* __restrict__ fb1,
                                            const float* __restrict__ fW2,
                                            const float* __restrict__ fb2,
                                            f16* __restrict__ table,
                                            const float* __restrict__ in2f_W,
                                            const float* __restrict__ oW1,
                                            const float* __restrict__ oW2,
                                            f16* __restrict__ wsw,
                                            int* __restrict__ cursor) {
  __shared__ float hid[8 * 128];
  int t = threadIdx.x;
  int bid = blockIdx.x;

  if (bid >= 843) { cursor[(bid - 843) * 256 + t] = 0; return; }

  if (bid >= 771) {
    // weight convert: W[k][col] f32 -> wsw[mm] fp16 [col][k], two swzW k-halves
    int bid2 = bid - 771;
    int mm = bid2 >> 3;
    int tloc = (bid2 & 7) * 256 + t;
    int col = tloc & 127, k0 = (tloc >> 7) << 3;
    const float* src = mm < 3 ? in2f_W + (size_t)mm * 16384
                     : mm < 6 ? oW1 + (size_t)(mm - 3) * 16384
                              : oW2 + (size_t)(mm - 6) * 16384;
    f16x8 v;
    #pragma unroll
    for (int kk = 0; kk < 8; ++kk) v[kk] = (f16)src[(k0 + kk) * 128 + col];
    *(f16x8*)((char*)wsw + (size_t)mm * 32768 + (k0 >> 6) * 16384 + swzW(col, k0 & 63)) = v;
    return;
  }

  // wide table gen: 8 entries per block, thread = (entry e, 4 cols at q*4)
  int l = bid / 257, rem = bid % 257;
  int e = t >> 5, q = t & 31;
  int ti = rem * 8 + e;
  const float* W1 = fW1 + (size_t)l * 20 * 128;
  const float* B1 = fb1 + (size_t)l * 128;
  const float* W2 = fW2 + (size_t)l * 128 * 128;
  const float* B2 = fb2 + (size_t)l * 128;

  const float width = CUTOFF_F / 19.0f;
  const float coeff = -0.5f / (width * width);
  const float dstep = CUTOFF_F / (float)TBINS;
  float d = (float)ti * dstep;

  float4 h4 = *(const float4*)&B1[q * 4];
  #pragma unroll
  for (int r = 0; r < 20; ++r) {
    float diff = d - (float)r * width;
    float fr = expf(coeff * diff * diff);
    float4 w4 = *(const float4*)&W1[r * 128 + q * 4];
    h4.x += fr * w4.x; h4.y += fr * w4.y; h4.z += fr * w4.z; h4.w += fr * w4.w;
  }
  *(float4*)&hid[e * 128 + q * 4] =
      make_float4(sspf(h4.x), sspf(h4.y), sspf(h4.z), sspf(h4.w));
  __syncthreads();

  float4 o4 = *(const float4*)&B2[q * 4];
  const float4* W2g = (const float4*)W2;
  #pragma unroll 4
  for (int g = 0; g < 128; ++g) {
    float hv = hid[e * 128 + g];
    float4 w4 = W2g[g * 32 + q];
    o4.x += hv * w4.x; o4.y += hv * w4.y; o4.z += hv * w4.z; o4.w += hv * w4.w;
  }

  if (ti < TROWS) {
    float fc = (d < CUTOFF_F) ? 0.5f * (cosf(d * 0.62831853071795865f) + 1.0f) : 0.0f;
    f16x4 hv = { (f16)(o4.x * fc), (f16)(o4.y * fc), (f16)(o4.z * fc), (f16)(o4.w * fc) };
    *(f16x4*)((f16*)table + ((size_t)l * TROWS + ti) * 128 + q * 4) = hv;
  }
}

// ============ pg0: pair placement (0..2047) + MFMA gemm_in layer0 (2048..2303) ============
__global__ __launch_bounds__(256) void pg0(const int* __restrict__ Z,
                                           const float* __restrict__ emb,
                                           const f16* __restrict__ Wsw,
                                           const float* __restrict__ bias,
                                           f16* __restrict__ hout,
                                           const int* __restrict__ idx_i,
                                           const int* __restrict__ idx_j,
                                           const float* __restrict__ R,
                                           int* __restrict__ cursor,
                                           int* __restrict__ pjd) {
  __shared__ char smem[49152];
  char* Al = smem;            // 16 KB
  char* Wl = smem + 16384;    // 32 KB
  int t = threadIdx.x;

  if (blockIdx.x < 2048) {
    int p = blockIdx.x * 256 + t;
    int i = idx_i[p], j = idx_j[p];
    float dx = R[(size_t)i*3+0] - R[(size_t)j*3+0];
    float dy = R[(size_t)i*3+1] - R[(size_t)j*3+1];
    float dz = R[(size_t)i*3+2] - R[(size_t)j*3+2];
    float d = sqrtf(dx*dx + dy*dy + dz*dz);
    if (d < CUTOFF_F) {
      int bin = __float2int_rn(d * ((float)TBINS / CUTOFF_F));
      int slot = atomicAdd(&cursor[i], 1);
      if (slot < CAP) pjd[i * CAP + slot] = j | (bin << 14);
    }
    return;
  }

  size_t rbase = (size_t)(blockIdx.x - 2048) * 64;
  #pragma unroll
  for (int i = 0; i < 8; ++i) {
    int idx = i * 256 + t;
    int r = idx >> 5, q = idx & 31;
    int z = Z[rbase + r];
    float4 v = ((const float4*)emb)[(size_t)z * 32 + q];
    f16x4 h = { (f16)v.x, (f16)v.y, (f16)v.z, (f16)v.w };
    *(f16x4*)(Al + swz(r, q * 4)) = h;
  }
  #pragma unroll
  for (int i = 0; i < 8; ++i) ((uint4*)Wl)[i * 256 + t] = ((const uint4*)Wsw)[i * 256 + t];
  __syncthreads();

  int w = t >> 6, lane = t & 63;
  int lo = lane & 15, hi = lane >> 4;
  f16x8 fa[4];
  #pragma unroll
  for (int s = 0; s < 4; ++s)
    fa[s] = *(f16x8*)(Al + swz(16 * w + lo, s * 32 + hi * 8));

  #pragma unroll
  for (int cb = 0; cb < 8; ++cb) {
    f32x4 acc = {0.0f, 0.0f, 0.0f, 0.0f};
    #pragma unroll
    for (int s = 0; s < 4; ++s) {
      f16x8 fb = *(f16x8*)(Wl + (s >> 1) * 16384 + swzW(cb * 16 + lo, (s & 1) * 32 + hi * 8));
      acc = __builtin_amdgcn_mfma_f32_16x16x32_f16(fa[s], fb, acc, 0, 0, 0);
    }
    int col = cb * 16 + lo;
    float bc = bias[col];
    #pragma unroll
    for (int j = 0; j < 4; ++j)
      hout[(rbase + 16 * w + hi * 4 + j) * 128 + col] = (f16)(acc[j] + bc);
  }
}

// ============ aggfuse: 16 atoms/block, 512 thr, 24 KB LDS ============
template <int FIRST, int HAS_NEXT>
__global__ __launch_bounds__(512, 8) void aggfuse(const int* __restrict__ pjd,
                                                  const int* __restrict__ cnt,
                                                  const f16* __restrict__ hin,
                                                  const f16* __restrict__ tabL,
                                                  const f16* __restrict__ W1sw,
                                                  const float* __restrict__ ob1,
                                                  const f16* __restrict__ W2sw,
                                                  const float* __restrict__ ob2,
                                                  const int* __restrict__ Z,
                                                  const float* __restrict__ emb,
                                                  float* __restrict__ x,
                                                  const f16* __restrict__ Wnsw,
                                                  const float* __restrict__ bn,
                                                  f16* __restrict__ hout) {
  __shared__ char smem[24576];
  char* Wl  = smem;            // 16 KB (half-K W tile)
  char* AlT = smem + 16384;    // 4 KB
  char* Tl  = smem + 20480;    // 4 KB
  int tid = threadIdx.x;
  int wv = tid >> 6, lane = tid & 63;
  int s = lane >> 4, c = lane & 15;
  int rbase = blockIdx.x * 16;
  const int S = (TBINS << 14);   // sentinel -> zero table row, h[0]

  // ---- agg phase: atom = wv*2 + (s&1); halves (s>>1) split pairs mod 4 ----
  {
    int a = rbase + wv * 2 + (s & 1);
    int half = s >> 1;
    int p0 = a * CAP;
    int n = min(cnt[a], CAP);
    int nh = half * 2;

    int m = (n + 3) >> 2;
    m = max(m, __shfl_xor(m, 16, 64));
    m = max(m, __shfl_xor(m, 32, 64));

    float acc[8];
    #pragma unroll
    for (int q = 0; q < 8; ++q) acc[q] = 0.0f;

    int vA  = (nh < n)     ? pjd[p0 + nh]     : S;
    int vB  = (nh + 1 < n) ? pjd[p0 + nh + 1] : S;
    int vA1 = (nh + 4 < n) ? pjd[p0 + nh + 4] : S;
    int vB1 = (nh + 5 < n) ? pjd[p0 + nh + 5] : S;
    uint4 wA = ldtab(tabL, vA, c), hA = ldh(hin, vA, c);
    uint4 wB = ldtab(tabL, vB, c), hB = ldh(hin, vB, c);

    for (int it = 0; it < m; ++it) {
      int k2 = 4 * (it + 2) + nh;
      int vA2 = (k2 < n)     ? pjd[p0 + k2]     : S;
      int vB2 = (k2 + 1 < n) ? pjd[p0 + k2 + 1] : S;
      uint4 wAn = ldtab(tabL, vA1, c), hAn = ldh(hin, vA1, c);
      uint4 wBn = ldtab(tabL, vB1, c), hBn = ldh(hin, vB1, c);
      dot8(acc, wA, hA);
      dot8(acc, wB, hB);
      wA = wAn; hA = hAn; wB = wBn; hB = hBn;
      vA1 = vA2; vB1 = vB2;
    }

    #pragma unroll
    for (int q = 0; q < 8; ++q) acc[q] += __shfl_xor(acc[q], 32, 64);

    if (s < 2) {
      int row = wv * 2 + s;
      f16x8 pk;
      #pragma unroll
      for (int q = 0; q < 8; ++q) pk[q] = (f16)acc[q];
      *(f16x8*)(AlT + swz(row, c * 8)) = pk;
    }
  }
  __syncthreads();

  // ---- fuse phase: 8 waves, wave w owns col-block w (16 cols), 16 rows ----
  int lo = c, hi = s;
  int col = wv * 16 + lo;

  // residual prefetch (hidden under gemm1)
  float res[4];
  if (FIRST) {
    #pragma unroll
    for (int j = 0; j < 4; ++j) {
      int z = Z[rbase + hi * 4 + j];
      res[j] = emb[(size_t)z * 128 + col];
    }
  } else {
    #pragma unroll
    for (int j = 0; j < 4; ++j)
      res[j] = x[(size_t)(rbase + hi * 4 + j) * 128 + col];
  }

  // gemm1: Tl = ssp(AlT @ oW1 + b1)
  {
    f16x8 fa[4];
    #pragma unroll
    for (int ss = 0; ss < 4; ++ss)
      fa[ss] = *(f16x8*)(AlT + swz(lo, ss * 32 + hi * 8));
    f32x4 acc = {0.0f, 0.0f, 0.0f, 0.0f};
    #pragma unroll
    for (int half = 0; half < 2; ++half) {
      #pragma unroll
      for (int i = 0; i < 2; ++i)
        ((uint4*)Wl)[i * 512 + tid] = ((const uint4*)W1sw)[half * 1024 + i * 512 + tid];
      __syncthreads();
      #pragma unroll
      for (int sh = 0; sh < 2; ++sh) {
        int ss = half * 2 + sh;
        f16x8 fb = *(f16x8*)(Wl + swzW(col, sh * 32 + hi * 8));
        acc = __builtin_amdgcn_mfma_f32_16x16x32_f16(fa[ss], fb, acc, 0, 0, 0);
      }
      __syncthreads();
    }
    float bc = ob1[col];
    #pragma unroll
    for (int j = 0; j < 4; ++j)
      *(f16*)(Tl + swz(hi * 4 + j, col)) = (f16)sspf(acc[j] + bc);
  }
  __syncthreads();

  // gemm2: x_new = res + Tl @ oW2 + b2 -> x and AlT
  {
    f32x4 acc = {0.0f, 0.0f, 0.0f, 0.0f};
    f16x8 fa[4];
    #pragma unroll
    for (int half = 0; half < 2; ++half) {
      #pragma unroll
      for (int i = 0; i < 2; ++i)
        ((uint4*)Wl)[i * 512 + tid] = ((const uint4*)W2sw)[half * 1024 + i * 512 + tid];
      __syncthreads();
      if (half == 0) {
        #pragma unroll
        for (int ss = 0; ss < 4; ++ss)
          fa[ss] = *(f16x8*)(Tl + swz(lo, ss * 32 + hi * 8));
      }
      #pragma unroll
      for (int sh = 0; sh < 2; ++sh) {
        int ss = half * 2 + sh;
        f16x8 fb = *(f16x8*)(Wl + swzW(col, sh * 32 + hi * 8));
        acc = __builtin_amdgcn_mfma_f32_16x16x32_f16(fa[ss], fb, acc, 0, 0, 0);
      }
      __syncthreads();
    }
    float bc = ob2[col];
    #pragma unroll
    for (int j = 0; j < 4; ++j) {
      int r = hi * 4 + j;
      float xn = res[j] + acc[j] + bc;
      x[(size_t)(rbase + r) * 128 + col] = xn;
      if (HAS_NEXT) *(f16*)(AlT + swz(r, col)) = (f16)xn;
    }
  }

  if (HAS_NEXT) {
    __syncthreads();
    f32x4 acc = {0.0f, 0.0f, 0.0f, 0.0f};
    f16x8 fa[4];
    #pragma unroll
    for (int half = 0; half < 2; ++half) {
      #pragma unroll
      for (int i = 0; i < 2; ++i)
        ((uint4*)Wl)[i * 512 + tid] = ((const uint4*)Wnsw)[half * 1024 + i * 512 + tid];
      __syncthreads();
      if (half == 0) {
        #pragma unroll
        for (int ss = 0; ss < 4; ++ss)
          fa[ss] = *(f16x8*)(AlT + swz(lo, ss * 32 + hi * 8));
      }
      #pragma unroll
      for (int sh = 0; sh < 2; ++sh) {
        int ss = half * 2 + sh;
        f16x8 fb = *(f16x8*)(Wl + swzW(col, sh * 32 + hi * 8));
        acc = __builtin_amdgcn_mfma_f32_16x16x32_f16(fa[ss], fb, acc, 0, 0, 0);
      }
      __syncthreads();
    }
    float bc = bn[col];
    #pragma unroll
    for (int j = 0; j < 4; ++j)
      hout[(size_t)(rbase + hi * 4 + j) * 128 + col] = (f16)(acc[j] + bc);
  }
}

// ============ launcher ============
extern "C" void kernel_launch(void* const* d_in, const int* in_sizes, int n_in,
                              void* d_out, int out_size, void* d_ws, size_t ws_size,
                              hipStream_t stream) {
  const int*   Z      = (const int*)d_in[0];
  const float* R      = (const float*)d_in[1];
  const int*   idx_i  = (const int*)d_in[2];
  const int*   idx_j  = (const int*)d_in[3];
  const float* emb    = (const float*)d_in[4];
  const float* in2f_W = (const float*)d_in[5];
  const float* in2f_b = (const float*)d_in[6];
  const float* fW1    = (const float*)d_in[7];
  const float* fb1    = (const float*)d_in[8];
  const float* fW2    = (const float*)d_in[9];
  const float* fb2    = (const float*)d_in[10];
  const float* oW1    = (const float*)d_in[11];
  const float* ob1    = (const float*)d_in[12];
  const float* oW2    = (const float*)d_in[13];
  const float* ob2    = (const float*)d_in[14];
  float* x = (float*)d_out;

  char* ws = (char*)d_ws;
  int*  cursor = (int*) (ws + 0x000000);   // 64 KB
  int*  pjd    = (int*) (ws + 0x010000);   // 16384*80*4 = 5 MB
  f16*  table  = (f16*) (ws + 0x510000);   // 3 x 2049 x 128 x 2B = 1.5 MB
  f16*  h0     = (f16*) (ws + 0x6A0000);   // 4 MB
  f16*  h1     = (f16*) (ws + 0xAA0000);   // 4 MB
  f16*  wsw    = (f16*) (ws + 0xEA0000);   // 9 x 32 KB

  prep<<<907, 256, 0, stream>>>(fW1, fb1, fW2, fb2, table, in2f_W, oW1, oW2, wsw, cursor);
  pg0<<<2304, 256, 0, stream>>>(Z, emb, wsw, in2f_b, h0, idx_i, idx_j, R, cursor, pjd);

  aggfuse<1, 1><<<NATOMS / 16, 512, 0, stream>>>(pjd, cursor, h0, table + 0 * (size_t)TROWS * 128,
                                                 wsw + 3 * 16384, ob1,
                                                 wsw + 6 * 16384, ob2,
                                                 Z, emb, x,
                                                 wsw + 1 * 16384, in2f_b + 128, h1);
  aggfuse<0, 1><<<NATOMS / 16, 512, 0, stream>>>(pjd, cursor, h1, table + 1 * (size_t)TROWS * 128,
                                                 wsw + 4 * 16384, ob1 + 128,
                                                 wsw + 7 * 16384, ob2 + 128,
                                                 Z, emb, x,
                                                 wsw + 2 * 16384, in2f_b + 256, h0);
  aggfuse<0, 0><<<NATOMS / 16, 512, 0, stream>>>(pjd, cursor, h0, table + 2 * (size_t)TROWS * 128,
                                                 wsw + 5 * 16384, ob1 + 256,
                                                 wsw + 8 * 16384, ob2 + 256,
                                                 Z, emb, x, nullptr, nullptr, nullptr);
}